// Round 7
// baseline (1441.942 us; speedup 1.0000x reference)
//
#include <hip/hip_runtime.h>
#include <math.h>

#define KCODES 4096
#define DIM    256
#define HW     4096
#define NPIX   65536
#define NQ     16777216   // 16*256*64*64
#define EPSW   1.0e-4f    // candidate window (>= 2*(ulp(256)+2*deltam))
#define NSLICE 4
#define SLK    1024       // codes per slice

typedef _Float16 f16x8 __attribute__((ext_vector_type(8)));
typedef float    f32x4 __attribute__((ext_vector_type(4)));

// top4 insert, strict < (keeps lowest k on equal d given ascending-k feed)
#define INS4(V, I, dd, kk) do { \
  if ((dd) < V[3]) { \
    if ((dd) < V[1]) { \
      V[3]=V[2]; I[3]=I[2]; V[2]=V[1]; I[2]=I[1]; \
      if ((dd) < V[0]) { V[1]=V[0]; I[1]=I[0]; V[0]=(dd); I[0]=(kk); } \
      else             { V[1]=(dd); I[1]=(kk); } \
    } else { \
      if ((dd) < V[2]) { V[3]=V[2]; I[3]=I[2]; V[2]=(dd); I[2]=(kk); } \
      else             { V[3]=(dd); I[3]=(kk); } \
    } } } while(0)

// ---------------------------------------------------------------------------
// np-exact helpers (bit-replicate numpy f32 semantics — proven in R3)
// ---------------------------------------------------------------------------
__global__ __launch_bounds__(256) void ee_np_kernel(const float* __restrict__ emb,
                                                    float* __restrict__ ee) {
#pragma clang fp contract(off)
    const int k = blockIdx.x * 256 + threadIdx.x;
    const float* a = emb + (size_t)k * DIM;
    float res[2];
    #pragma unroll
    for (int h = 0; h < 2; ++h) {
        const float* b = a + h * 128;
        float r[8];
        #pragma unroll
        for (int j = 0; j < 8; ++j) { const float x = b[j]; r[j] = x * x; }
        for (int i = 8; i < 128; i += 8) {
            #pragma unroll
            for (int j = 0; j < 8; ++j) { const float x = b[i + j]; r[j] += x * x; }
        }
        res[h] = ((r[0] + r[1]) + (r[2] + r[3])) + ((r[4] + r[5]) + (r[6] + r[7]));
    }
    ee[k] = res[0] + res[1];
}

__global__ __launch_bounds__(256) void zz_np_kernel(const float* __restrict__ z,
                                                    float* __restrict__ zz) {
#pragma clang fp contract(off)
    const int n  = blockIdx.x * 256 + threadIdx.x;
    const int b  = n >> 12;
    const int hw = n & (HW - 1);
    const float* base = z + (size_t)b * DIM * HW + hw;
    float res[2];
    #pragma unroll
    for (int h = 0; h < 2; ++h) {
        const float* p = base + (size_t)(h * 128) * HW;
        float r[8];
        #pragma unroll
        for (int j = 0; j < 8; ++j) { const float x = p[(size_t)j * HW]; r[j] = x * x; }
        for (int i = 8; i < 128; i += 8) {
            #pragma unroll
            for (int j = 0; j < 8; ++j) { const float x = p[(size_t)(i + j) * HW]; r[j] += x * x; }
        }
        res[h] = ((r[0] + r[1]) + (r[2] + r[3])) + ((r[4] + r[5]) + (r[6] + r[7]));
    }
    zz[n] = res[0] + res[1];
}

__device__ float np_dist(const float* __restrict__ z, const float* __restrict__ emb,
                         const float* __restrict__ zz, const float* __restrict__ ee,
                         int n, int k) {
    const int b = n >> 12, hw = n & (HW - 1);
    const float* zp = z + (size_t)b * DIM * HW + hw;
    const float* ep = emb + (size_t)k * DIM;
    float m = 0.0f;
    for (int i = 0; i < DIM; ++i) m = fmaf(zp[(size_t)i * HW], ep[i], m);
    const float t = zz[n] + ee[k];
    return t - 2.0f * m;   // == fl(t - 2m) either way (product exact)
}

// ---------------------------------------------------------------------------
// FAST path kernels
// ---------------------------------------------------------------------------
// emb -> tiled fp16 hi/lo, scaled by 4096 (exact pow2). Tile layout:
// addr(halfs) = (k>>7)*32768 + (d>>5)*4096 + (k&127)*32 + (d&31)
__global__ __launch_bounds__(256) void cvt_emb_kernel(const float* __restrict__ emb,
                                                      ushort* __restrict__ eh,
                                                      ushort* __restrict__ el) {
    const int t = threadIdx.x;
    const int k = blockIdx.x * 4 + (t >> 6);
    const int seg = t & 63;                       // 4-elem segment
    const float4 v = *reinterpret_cast<const float4*>(emb + (size_t)k * DIM + seg * 4);
    union H4 { _Float16 h[4]; short4 s; } uh, ul;
    const float vv[4] = {v.x, v.y, v.z, v.w};
    #pragma unroll
    for (int j = 0; j < 4; ++j) {
        const float es = vv[j] * 4096.0f;
        const _Float16 h = (_Float16)es;
        uh.h[j] = h;
        ul.h[j] = (_Float16)(es - (float)h);
    }
    const int s = seg >> 3, din = (seg & 7) * 4;
    const size_t addr = (size_t)(k >> 7) * 32768 + s * 4096 + (k & 127) * 32 + din;
    *reinterpret_cast<short4*>(eh + addr) = uh.s;
    *reinterpret_cast<short4*>(el + addr) = ul.s;
}

// z (NCHW) -> transposed tiled fp16 hi/lo [pixel][dim]:
// addr(halfs) = (px>>7)*32768 + (d>>5)*4096 + (px&127)*32 + (d&31)
__global__ __launch_bounds__(256) void cvt_z_kernel(const float* __restrict__ z,
                                                    ushort* __restrict__ zh,
                                                    ushort* __restrict__ zl) {
    __shared__ float ls[64][65];
    const int t = threadIdx.x;
    const int bid = blockIdx.x;
    const int b = bid >> 8, cc = (bid >> 6) & 3, hh = bid & 63;
    const int col = t & 63, r0 = t >> 6;
    #pragma unroll
    for (int i = 0; i < 16; ++i) {
        const int r = i * 4 + r0;
        ls[r][col] = z[((size_t)(b * DIM + cc * 64 + r)) * HW + hh * 64 + col];
    }
    __syncthreads();
    const int pxl = t >> 2, cseg = t & 3;
    const int px = b * HW + hh * 64 + pxl;
    const int sg = cc * 2 + (cseg >> 1);
    union H8 { _Float16 h[8]; int4 v; } ha, hb, la, lb;
    #pragma unroll
    for (int j = 0; j < 16; ++j) {
        const float val = ls[cseg * 16 + j][pxl];
        const _Float16 h = (_Float16)val;
        const _Float16 l = (_Float16)(val - (float)h);
        if (j < 8) { ha.h[j] = h; la.h[j] = l; }
        else       { hb.h[j - 8] = h; lb.h[j - 8] = l; }
    }
    const size_t addr = (size_t)(px >> 7) * 32768 + sg * 4096 + (px & 127) * 32 + (cseg & 1) * 16;
    *reinterpret_cast<int4*>(zh + addr)     = ha.v;
    *reinterpret_cast<int4*>(zh + addr + 8) = hb.v;
    *reinterpret_cast<int4*>(zl + addr)     = la.v;
    *reinterpret_cast<int4*>(zl + addr + 8) = lb.v;
}

// MFMA distance pass: block = 64 pixels x 1024-code slice.
// slice = (bid>>1)&3, so with round-robin blockIdx->XCD dispatch each XCD
// touches ONE 1MB code slice -> code fragment loads stay L2-hot.
// z tile LDS-resident (staged once, XOR-swizzled); per-pixel per-slice top4.
__global__ __launch_bounds__(256, 2) void gemm_kernel(const ushort* __restrict__ eh,
                                                      const ushort* __restrict__ el,
                                                      const ushort* __restrict__ zh,
                                                      const ushort* __restrict__ zl,
                                                      const float* __restrict__ ee,
                                                      const float* __restrict__ zz,
                                                      float* __restrict__ sv,
                                                      int* __restrict__ si) {
    __shared__ __align__(16) char zlds[2][32768];   // [hi/lo][8 s][64 px][64 B], swizzled

    const int t = threadIdx.x;
    const int lane = t & 63, w = t >> 6;
    const int l15 = lane & 15, l4 = lane >> 4;
    const int bid = blockIdx.x;
    const int slice = (bid >> 1) & 3;               // XCD-pinned code slice
    const int mtile = (bid >> 3) * 2 + (bid & 1);   // 0..1023
    const int px0 = mtile * 64;
    const size_t hb = (size_t)(px0 >> 7) * 32768 + (size_t)(px0 & 64) * 32;

    // ---- stage z tile once (coalesced global, swizzled ds_write) ----
    {
        const int pxl = t >> 2;
        const int kb  = (t & 3) * 16;               // byte offset within 64B row
        #pragma unroll
        for (int s = 0; s < 8; ++s) {
            const size_t gh = hb + s * 4096 + pxl * 32 + (t & 3) * 8;
            const int4 vh = *reinterpret_cast<const int4*>(zh + gh);
            const int4 vl = *reinterpret_cast<const int4*>(zl + gh);
            const int db = s * 4096 + ((pxl * 64 + kb) ^ ((pxl & 7) << 4));
            *reinterpret_cast<int4*>(zlds[0] + db) = vh;
            *reinterpret_cast<int4*>(zlds[1] + db) = vl;
        }
    }
    float zzr[4];
    #pragma unroll
    for (int ni = 0; ni < 4; ++ni) zzr[ni] = zz[px0 + ni * 16 + l15];
    __syncthreads();

    float Tv[4][4]; int Ti[4][4];
    #pragma unroll
    for (int ni = 0; ni < 4; ++ni)
        #pragma unroll
        for (int j = 0; j < 4; ++j) { Tv[ni][j] = 3.0e38f; Ti[ni][j] = 0; }

    const size_t cb = (size_t)(w * 32 + l15) * 32 + l4 * 8;   // code-frag lane offset

    for (int p = 0; p < 8; ++p) {
        // ee for this chunk's rows (per-lane, consumed in epilogue)
        float eer[2][4];
        #pragma unroll
        for (int mi = 0; mi < 2; ++mi)
            #pragma unroll
            for (int r = 0; r < 4; ++r)
                eer[mi][r] = ee[slice * SLK + p * 128 + w * 32 + mi * 16 + l4 * 4 + r];

        f32x4 acc[2][4];
        #pragma unroll
        for (int mi = 0; mi < 2; ++mi)
            #pragma unroll
            for (int ni = 0; ni < 4; ++ni)
                acc[mi][ni] = (f32x4){0.0f, 0.0f, 0.0f, 0.0f};

        const size_t pb = (size_t)(slice * 8 + p) * 32768 + cb;
        #pragma unroll
        for (int s = 0; s < 8; ++s) {
            f16x8 aH[2], aL[2];
            #pragma unroll
            for (int mi = 0; mi < 2; ++mi) {
                const size_t g = pb + (size_t)s * 4096 + mi * 512;
                aH[mi] = *reinterpret_cast<const f16x8*>(eh + g);
                aL[mi] = *reinterpret_cast<const f16x8*>(el + g);
            }
            f16x8 bH[4], bL[4];
            #pragma unroll
            for (int ni = 0; ni < 4; ++ni) {
                const int px = ni * 16 + l15;
                const int ob = s * 4096 + ((px * 64 + l4 * 16) ^ ((px & 7) << 4));
                bH[ni] = *reinterpret_cast<const f16x8*>(zlds[0] + ob);
                bL[ni] = *reinterpret_cast<const f16x8*>(zlds[1] + ob);
            }
            #pragma unroll
            for (int mi = 0; mi < 2; ++mi)
                #pragma unroll
                for (int ni = 0; ni < 4; ++ni) {
                    acc[mi][ni] = __builtin_amdgcn_mfma_f32_16x16x32_f16(aH[mi], bH[ni], acc[mi][ni], 0, 0, 0);
                    acc[mi][ni] = __builtin_amdgcn_mfma_f32_16x16x32_f16(aH[mi], bL[ni], acc[mi][ni], 0, 0, 0);
                    acc[mi][ni] = __builtin_amdgcn_mfma_f32_16x16x32_f16(aL[mi], bH[ni], acc[mi][ni], 0, 0, 0);
                }
        }
        // epilogue: d = fl((zz+ee) - acc*2^-11); top4 (ascending k per lane)
        #pragma unroll
        for (int ni = 0; ni < 4; ++ni) {
            const float zzc = zzr[ni];
            #pragma unroll
            for (int mi = 0; mi < 2; ++mi)
                #pragma unroll
                for (int r = 0; r < 4; ++r) {
                    const float tt = zzc + eer[mi][r];
                    const float d = fmaf(acc[mi][ni][r], -4.8828125e-4f, tt);
                    const int k = slice * SLK + p * 128 + w * 32 + mi * 16 + l4 * 4 + r;
                    INS4(Tv[ni], Ti[ni], d, k);
                }
        }
    }

    // cross-lane merge within wave (lanes sharing the same pixel col)
    #pragma unroll
    for (int ni = 0; ni < 4; ++ni) {
        #pragma unroll
        for (int m = 16; m <= 32; m <<= 1) {
            float ov[4]; int oi[4];
            #pragma unroll
            for (int j = 0; j < 4; ++j) {
                ov[j] = __shfl_xor(Tv[ni][j], m, 64);
                oi[j] = __shfl_xor(Ti[ni][j], m, 64);
            }
            #pragma unroll
            for (int j = 0; j < 4; ++j) INS4(Tv[ni], Ti[ni], ov[j], oi[j]);
        }
    }

    __syncthreads();   // all waves done reading zlds before aliasing it
    float (*mv)[64][4]  = reinterpret_cast<float (*)[64][4]>(&zlds[0][0]);
    int   (*mi_)[64][4] = reinterpret_cast<int (*)[64][4]>(&zlds[0][16384]);
    if (lane < 16) {
        #pragma unroll
        for (int ni = 0; ni < 4; ++ni)
            #pragma unroll
            for (int j = 0; j < 4; ++j) {
                mv[w][ni * 16 + lane][j]  = Tv[ni][j];
                mi_[w][ni * 16 + lane][j] = Ti[ni][j];
            }
    }
    __syncthreads();
    if (t < 64) {
        float fv[4]; int fi[4];
        #pragma unroll
        for (int j = 0; j < 4; ++j) { fv[j] = mv[0][t][j]; fi[j] = mi_[0][t][j]; }
        #pragma unroll
        for (int ww = 1; ww < 4; ++ww)
            #pragma unroll
            for (int j = 0; j < 4; ++j) INS4(fv, fi, mv[ww][t][j], mi_[ww][t][j]);
        const int px = px0 + t;
        *reinterpret_cast<float4*>(sv + ((size_t)px * NSLICE + slice) * 4) = make_float4(fv[0], fv[1], fv[2], fv[3]);
        *reinterpret_cast<int4*>(si + ((size_t)px * NSLICE + slice) * 4)   = make_int4(fi[0], fi[1], fi[2], fi[3]);
    }
}

// merge per-slice top4 (slice-ascending = k-ascending ties) + certify/resolve
__global__ __launch_bounds__(256) void merge_resolve_kernel(const float* __restrict__ sv,
                                                            const int* __restrict__ si,
                                                            const float* __restrict__ z,
                                                            const float* __restrict__ emb,
                                                            const float* __restrict__ zz,
                                                            const float* __restrict__ ee,
                                                            int* __restrict__ idxf,
                                                            int* __restrict__ cnt,
                                                            int* __restrict__ rlist) {
    const int n = blockIdx.x * 256 + threadIdx.x;
    float v[4]; int id[4];
    {
        const float4 v0 = *reinterpret_cast<const float4*>(sv + (size_t)n * NSLICE * 4);
        const int4   i0 = *reinterpret_cast<const int4*>(si + (size_t)n * NSLICE * 4);
        v[0] = v0.x; v[1] = v0.y; v[2] = v0.z; v[3] = v0.w;
        id[0] = i0.x; id[1] = i0.y; id[2] = i0.z; id[3] = i0.w;
        #pragma unroll
        for (int s = 1; s < NSLICE; ++s) {
            const float4 vs = *reinterpret_cast<const float4*>(sv + ((size_t)n * NSLICE + s) * 4);
            const int4   is = *reinterpret_cast<const int4*>(si + ((size_t)n * NSLICE + s) * 4);
            INS4(v, id, vs.x, is.x);
            INS4(v, id, vs.y, is.y);
            INS4(v, id, vs.z, is.z);
            INS4(v, id, vs.w, is.w);
        }
    }
    const float lim = v[0] + EPSW;
    if (v[1] > lim) { idxf[n] = id[0]; return; }
    if (v[3] <= lim) {                       // can't certify top4 covers window
        idxf[n] = id[0];                     // provisional; rescan overwrites
        const int pos = atomicAdd(cnt, 1);
        rlist[pos] = n;
        return;
    }
    int ck[4]; int nc = 0;
    for (int j = 0; j < 4; ++j) if (v[j] <= lim) ck[nc++] = id[j];
    for (int a = 0; a < nc - 1; ++a)          // sort by k ascending
        for (int b2 = a + 1; b2 < nc; ++b2)
            if (ck[b2] < ck[a]) { int tmp = ck[a]; ck[a] = ck[b2]; ck[b2] = tmp; }
    float best = 0.0f; int bk = -1;
    for (int a = 0; a < nc; ++a) {
        const float d = np_dist(z, emb, zz, ee, n, ck[a]);
        if (bk < 0 || d < best) { best = d; bk = ck[a]; }
    }
    idxf[n] = bk;
}

// full np-exact rescan for flagged pixels (rare)
__global__ __launch_bounds__(256) void rescan_kernel(const float* __restrict__ z,
                                                     const float* __restrict__ emb,
                                                     const float* __restrict__ zz,
                                                     const float* __restrict__ ee,
                                                     const int* __restrict__ cnt,
                                                     const int* __restrict__ rlist,
                                                     int* __restrict__ idxf) {
#pragma clang fp contract(off)
    __shared__ float ls[DIM];
    __shared__ float bv[256];
    __shared__ int   bk[256];
    const int t = threadIdx.x;
    const int count = *cnt;
    for (int e = blockIdx.x; e < count; e += gridDim.x) {
        const int n = rlist[e];
        const int b = n >> 12, hw = n & (HW - 1);
        __syncthreads();
        ls[t] = z[((size_t)(b * DIM + t)) * HW + hw];
        __syncthreads();
        float bestd = 3.0e38f; int besti = -1;
        for (int j = 0; j < 16; ++j) {
            const int k = t + j * 256;
            const float* ep = emb + (size_t)k * DIM;
            float m = 0.0f;
            for (int i = 0; i < DIM; ++i) m = fmaf(ls[i], ep[i], m);
            const float d = (zz[n] + ee[k]) - 2.0f * m;
            if (besti < 0 || d < bestd) { bestd = d; besti = k; }
        }
        bv[t] = bestd; bk[t] = besti;
        __syncthreads();
        if (t == 0) {
            float bd = bv[0]; int bi = bk[0];
            for (int q = 1; q < 256; ++q)
                if (bv[q] < bd || (bv[q] == bd && bk[q] < bi)) { bd = bv[q]; bi = bk[q]; }
            idxf[n] = bi;
        }
    }
}

// gather z_q + idx output + loss partials (overwrites ALL of out's z_q region,
// including the per-slice scratch that lived there)
__global__ __launch_bounds__(256) void gather_kernel(const float* __restrict__ z,
                                                     const float* __restrict__ emb,
                                                     const int* __restrict__ idxf,
                                                     float* __restrict__ out,
                                                     float* __restrict__ part) {
    __shared__ int   idx_s[32];
    __shared__ float wred[4];
    const int tid = threadIdx.x;
    const int tx = tid & 31, ty = tid >> 5;
    const int m0 = blockIdx.x * 32;
    const int bimg = m0 >> 12, hw0 = m0 & (HW - 1);
    if (tid < 32) {
        const int ii = idxf[m0 + tid];
        idx_s[tid] = ii;
        out[NQ + m0 + tid] = (float)ii;
    }
    __syncthreads();
    float lsum = 0.0f;
    const size_t ebase = (size_t)idx_s[tx] * DIM;
    for (int it = 0; it < DIM / 8; ++it) {
        const int c = it * 8 + ty;
        const float e = emb[ebase + c];
        const size_t zoff = ((size_t)(bimg * DIM + c)) * HW + hw0 + tx;
        out[zoff] = e;
        const float diff = e - z[zoff];
        lsum += diff * diff;
    }
    #pragma unroll
    for (int off = 32; off >= 1; off >>= 1) lsum += __shfl_down(lsum, off, 64);
    if ((tid & 63) == 0) wred[tid >> 6] = lsum;
    __syncthreads();
    if (tid == 0) part[blockIdx.x] = wred[0] + wred[1] + wred[2] + wred[3];
}

__global__ __launch_bounds__(256) void loss_kernel(const float* __restrict__ part,
                                                   int nblk, float* __restrict__ out) {
    __shared__ float wred[4];
    const int tid = threadIdx.x;
    float s = 0.0f;
    for (int i = tid; i < nblk; i += 256) s += part[i];
    #pragma unroll
    for (int off = 32; off >= 1; off >>= 1) s += __shfl_down(s, off, 64);
    if ((tid & 63) == 0) wred[tid >> 6] = s;
    __syncthreads();
    if (tid == 0) {
        const float total = wred[0] + wred[1] + wred[2] + wred[3];
        out[NQ + NPIX] = 1.25f * total / 16777216.0f;
    }
}

// ---------------------------------------------------------------------------
// SAFE path: R3's proven fused VALU kernel (used when ws too small)
// ---------------------------------------------------------------------------
#define MP 32
#define KC 128
#define DC 32
__global__ __launch_bounds__(256) void safe_dist_kernel(const float* __restrict__ z,
                                                        const float* __restrict__ emb,
                                                        const float* __restrict__ ee,
                                                        const float* __restrict__ zz,
                                                        float* __restrict__ out,
                                                        float* __restrict__ part) {
    __shared__ float zs[MP][DIM + 4];
    __shared__ float est[DC][KC + 4];
    __shared__ float ee_s[KC];
    __shared__ float zz_s[MP];
    __shared__ float red_v[MP][33];
    __shared__ int   red_i[MP][33];
    __shared__ int   idx_s[MP];
    __shared__ float wred[4];

    const int tid = threadIdx.x;
    const int tx = tid & 31, ty = tid >> 5;
    const int m0 = blockIdx.x * MP;
    const int bimg = m0 >> 12, hw0 = m0 & (HW - 1);

    for (int c = ty; c < DIM; c += 8)
        zs[tx][c] = z[((size_t)(bimg * DIM + c)) * HW + hw0 + tx];
    if (tid < MP) zz_s[tid] = zz[m0 + tid];

    float minv[4]; int mini[4];
    #pragma unroll
    for (int p = 0; p < 4; ++p) { minv[p] = 3.0e38f; mini[p] = 0; }
    const int rl = tid >> 3, cl = tid & 7;

    for (int kc = 0; kc < KCODES / KC; ++kc) {
        float acc[4][4];
        #pragma unroll
        for (int p = 0; p < 4; ++p)
            #pragma unroll
            for (int q = 0; q < 4; ++q) acc[p][q] = 0.0f;
        for (int dc = 0; dc < DIM / DC; ++dc) {
            __syncthreads();
            if (dc == 0 && tid < KC) ee_s[tid] = ee[kc * KC + tid];
            #pragma unroll
            for (int it = 0; it < 4; ++it) {
                const int kl = it * 32 + rl;
                const float4 v = *reinterpret_cast<const float4*>(
                    emb + (size_t)(kc * KC + kl) * DIM + dc * DC + cl * 4);
                est[cl * 4 + 0][kl] = v.x;
                est[cl * 4 + 1][kl] = v.y;
                est[cl * 4 + 2][kl] = v.z;
                est[cl * 4 + 3][kl] = v.w;
            }
            __syncthreads();
            #pragma unroll
            for (int g = 0; g < DC / 4; ++g) {
                float4 zr[4];
                #pragma unroll
                for (int p = 0; p < 4; ++p)
                    zr[p] = *reinterpret_cast<const float4*>(&zs[ty * 4 + p][dc * DC + g * 4]);
                float4 er[4];
                #pragma unroll
                for (int j = 0; j < 4; ++j)
                    er[j] = *reinterpret_cast<const float4*>(&est[g * 4 + j][tx * 4]);
                #pragma unroll
                for (int p = 0; p < 4; ++p) {
                    acc[p][0] = fmaf(zr[p].x, er[0].x, acc[p][0]);
                    acc[p][0] = fmaf(zr[p].y, er[1].x, acc[p][0]);
                    acc[p][0] = fmaf(zr[p].z, er[2].x, acc[p][0]);
                    acc[p][0] = fmaf(zr[p].w, er[3].x, acc[p][0]);
                    acc[p][1] = fmaf(zr[p].x, er[0].y, acc[p][1]);
                    acc[p][1] = fmaf(zr[p].y, er[1].y, acc[p][1]);
                    acc[p][1] = fmaf(zr[p].z, er[2].y, acc[p][1]);
                    acc[p][1] = fmaf(zr[p].w, er[3].y, acc[p][1]);
                    acc[p][2] = fmaf(zr[p].x, er[0].z, acc[p][2]);
                    acc[p][2] = fmaf(zr[p].y, er[1].z, acc[p][2]);
                    acc[p][2] = fmaf(zr[p].z, er[2].z, acc[p][2]);
                    acc[p][2] = fmaf(zr[p].w, er[3].z, acc[p][2]);
                    acc[p][3] = fmaf(zr[p].x, er[0].w, acc[p][3]);
                    acc[p][3] = fmaf(zr[p].y, er[1].w, acc[p][3]);
                    acc[p][3] = fmaf(zr[p].z, er[2].w, acc[p][3]);
                    acc[p][3] = fmaf(zr[p].w, er[3].w, acc[p][3]);
                }
            }
        }
        #pragma unroll
        for (int q = 0; q < 4; ++q) {
            const int kg = kc * KC + tx * 4 + q;
            const float en = ee_s[tx * 4 + q];
            #pragma unroll
            for (int p = 0; p < 4; ++p) {
                const float t = zz_s[ty * 4 + p] + en;
                const float d = t - 2.0f * acc[p][q];
                if (d < minv[p]) { minv[p] = d; mini[p] = kg; }
            }
        }
    }
    #pragma unroll
    for (int p = 0; p < 4; ++p) {
        red_v[ty * 4 + p][tx] = minv[p];
        red_i[ty * 4 + p][tx] = mini[p];
    }
    __syncthreads();
    if (tid < MP) {
        float bvv = red_v[tid][0]; int bii = red_i[tid][0];
        for (int q = 1; q < 32; ++q) {
            const float vq = red_v[tid][q]; const int iq = red_i[tid][q];
            if (vq < bvv || (vq == bvv && iq < bii)) { bvv = vq; bii = iq; }
        }
        idx_s[tid] = bii;
        out[NQ + m0 + tid] = (float)bii;
    }
    __syncthreads();
    float lsum = 0.0f;
    const size_t ebase = (size_t)idx_s[tx] * DIM;
    for (int it = 0; it < DIM / 8; ++it) {
        const int c = it * 8 + ty;
        const float e = emb[ebase + c];
        out[((size_t)(bimg * DIM + c)) * HW + hw0 + tx] = e;
        const float diff = e - zs[tx][c];
        lsum += diff * diff;
    }
    #pragma unroll
    for (int off = 32; off >= 1; off >>= 1) lsum += __shfl_down(lsum, off, 64);
    if ((tid & 63) == 0) wred[tid >> 6] = lsum;
    __syncthreads();
    if (tid == 0) part[blockIdx.x] = wred[0] + wred[1] + wred[2] + wred[3];
}

// ---------------------------------------------------------------------------
extern "C" void kernel_launch(void* const* d_in, const int* in_sizes, int n_in,
                              void* d_out, int out_size, void* d_ws, size_t ws_size,
                              hipStream_t stream) {
    const float* z   = (const float*)d_in[0];
    const float* emb = (const float*)d_in[1];
    float* out = (float*)d_out;
    char*  ws  = (char*)d_ws;

    // shared small region
    float* zz   = (float*)(ws + 0);            // 256K
    float* ee   = (float*)(ws + 262144);       // 16K
    float* part = (float*)(ws + 278528);       // 8K
    int*   cnt  = (int*)  (ws + 286720);       // 4K
    int*   rlst = (int*)  (ws + 290816);       // 256K
    int*   idxf = (int*)  (ws + 552960);       // 256K
    ushort* eh  = (ushort*)(ws + 3145728);     // 2M
    ushort* el  = (ushort*)(ws + 5242880);     // 2M
    ushort* zh  = (ushort*)(ws + 7340032);     // 32M
    ushort* zl  = (ushort*)(ws + 40894464);    // 32M
    const size_t REQ = 74448896;               // ~71 MB (granted in R4-R6)

    // per-slice top4 scratch carved from out's z_q region (overwritten by gather)
    float* sv = out;                            // 65536*4*4 f32 = 4 MB
    int*   si = (int*)out + (size_t)NPIX * NSLICE * 4;  // next 4 MB

    ee_np_kernel<<<KCODES / 256, 256, 0, stream>>>(emb, ee);
    zz_np_kernel<<<NPIX / 256, 256, 0, stream>>>(z, zz);

    if (ws_size >= REQ) {
        hipMemsetAsync(cnt, 0, 4, stream);
        cvt_emb_kernel<<<KCODES / 4, 256, 0, stream>>>(emb, eh, el);
        cvt_z_kernel<<<4096, 256, 0, stream>>>(z, zh, zl);
        gemm_kernel<<<NPIX / 64 * NSLICE, 256, 0, stream>>>(eh, el, zh, zl, ee, zz, sv, si);
        merge_resolve_kernel<<<NPIX / 256, 256, 0, stream>>>(sv, si, z, emb, zz, ee, idxf, cnt, rlst);
        rescan_kernel<<<64, 256, 0, stream>>>(z, emb, zz, ee, cnt, rlst, idxf);
        gather_kernel<<<NPIX / 32, 256, 0, stream>>>(z, emb, idxf, out, part);
        loss_kernel<<<1, 256, 0, stream>>>(part, NPIX / 32, out);
    } else {
        safe_dist_kernel<<<NPIX / MP, 256, 0, stream>>>(z, emb, ee, zz, out, part);
        loss_kernel<<<1, 256, 0, stream>>>(part, NPIX / MP, out);
    }
}

// Round 8
// 1194.657 us; speedup vs baseline: 1.2070x; 1.2070x over previous
//
#include <hip/hip_runtime.h>
#include <math.h>

#define KCODES 4096
#define DIM    256
#define HW     4096
#define NPIX   65536
#define NQ     16777216   // 16*256*64*64
#define EPSW   1.0e-4f    // candidate window (>= 2*(ulp(256)+2*deltam))

typedef _Float16 f16x8 __attribute__((ext_vector_type(8)));
typedef float    f32x4 __attribute__((ext_vector_type(4)));
typedef int      i32x4 __attribute__((ext_vector_type(4)));

static __device__ __forceinline__ i32x4 ntload16(const void* p) {
    return __builtin_nontemporal_load(reinterpret_cast<const i32x4*>(p));
}
static __device__ __forceinline__ void ntstore16(void* p, i32x4 v) {
    __builtin_nontemporal_store(v, reinterpret_cast<i32x4*>(p));
}

// XOR swizzle on tile-local byte offset: spreads 64B rows across banks
#define SWZ(x) ((x) ^ ((((x) >> 6) & 7) << 4))

// top4 insert, strict < (keeps lowest k on equal d given ascending-k feed)
#define INS4(V, I, dd, kk) do { \
  if ((dd) < V[3]) { \
    if ((dd) < V[1]) { \
      V[3]=V[2]; I[3]=I[2]; V[2]=V[1]; I[2]=I[1]; \
      if ((dd) < V[0]) { V[1]=V[0]; I[1]=I[0]; V[0]=(dd); I[0]=(kk); } \
      else             { V[1]=(dd); I[1]=(kk); } \
    } else { \
      if ((dd) < V[2]) { V[3]=V[2]; I[3]=I[2]; V[2]=(dd); I[2]=(kk); } \
      else             { V[3]=(dd); I[3]=(kk); } \
    } } } while(0)

// ---------------------------------------------------------------------------
// np-exact helpers (bit-replicate numpy f32 semantics — proven in R3)
// ---------------------------------------------------------------------------
__global__ __launch_bounds__(256) void ee_np_kernel(const float* __restrict__ emb,
                                                    float* __restrict__ ee) {
#pragma clang fp contract(off)
    const int k = blockIdx.x * 256 + threadIdx.x;
    const float* a = emb + (size_t)k * DIM;
    float res[2];
    #pragma unroll
    for (int h = 0; h < 2; ++h) {
        const float* b = a + h * 128;
        float r[8];
        #pragma unroll
        for (int j = 0; j < 8; ++j) { const float x = b[j]; r[j] = x * x; }
        for (int i = 8; i < 128; i += 8) {
            #pragma unroll
            for (int j = 0; j < 8; ++j) { const float x = b[i + j]; r[j] += x * x; }
        }
        res[h] = ((r[0] + r[1]) + (r[2] + r[3])) + ((r[4] + r[5]) + (r[6] + r[7]));
    }
    ee[k] = res[0] + res[1];
}

__global__ __launch_bounds__(256) void zz_np_kernel(const float* __restrict__ z,
                                                    float* __restrict__ zz) {
#pragma clang fp contract(off)
    const int n  = blockIdx.x * 256 + threadIdx.x;
    const int b  = n >> 12;
    const int hw = n & (HW - 1);
    const float* base = z + (size_t)b * DIM * HW + hw;
    float res[2];
    #pragma unroll
    for (int h = 0; h < 2; ++h) {
        const float* p = base + (size_t)(h * 128) * HW;
        float r[8];
        #pragma unroll
        for (int j = 0; j < 8; ++j) { const float x = p[(size_t)j * HW]; r[j] = x * x; }
        for (int i = 8; i < 128; i += 8) {
            #pragma unroll
            for (int j = 0; j < 8; ++j) { const float x = p[(size_t)(i + j) * HW]; r[j] += x * x; }
        }
        res[h] = ((r[0] + r[1]) + (r[2] + r[3])) + ((r[4] + r[5]) + (r[6] + r[7]));
    }
    zz[n] = res[0] + res[1];
}

__device__ float np_dist(const float* __restrict__ z, const float* __restrict__ emb,
                         const float* __restrict__ zz, const float* __restrict__ ee,
                         int n, int k) {
    const int b = n >> 12, hw = n & (HW - 1);
    const float* zp = z + (size_t)b * DIM * HW + hw;
    const float* ep = emb + (size_t)k * DIM;
    float m = 0.0f;
    for (int i = 0; i < DIM; ++i) m = fmaf(zp[(size_t)i * HW], ep[i], m);
    const float t = zz[n] + ee[k];
    return t - 2.0f * m;   // == fl(t - 2m) either way (product exact)
}

// ---------------------------------------------------------------------------
// FAST path kernels
// ---------------------------------------------------------------------------
// emb -> tiled fp16 hi/lo, scaled by 4096 (exact pow2). Tile layout:
// addr(halfs) = (k>>7)*32768 + (d>>5)*4096 + (k&127)*32 + (d&31)
__global__ __launch_bounds__(256) void cvt_emb_kernel(const float* __restrict__ emb,
                                                      ushort* __restrict__ eh,
                                                      ushort* __restrict__ el) {
    const int t = threadIdx.x;
    const int k = blockIdx.x * 4 + (t >> 6);
    const int seg = t & 63;                       // 4-elem segment
    const float4 v = *reinterpret_cast<const float4*>(emb + (size_t)k * DIM + seg * 4);
    union H4 { _Float16 h[4]; short4 s; } uh, ul;
    const float vv[4] = {v.x, v.y, v.z, v.w};
    #pragma unroll
    for (int j = 0; j < 4; ++j) {
        const float es = vv[j] * 4096.0f;
        const _Float16 h = (_Float16)es;
        uh.h[j] = h;
        ul.h[j] = (_Float16)(es - (float)h);
    }
    const int s = seg >> 3, din = (seg & 7) * 4;
    const size_t addr = (size_t)(k >> 7) * 32768 + s * 4096 + (k & 127) * 32 + din;
    *reinterpret_cast<short4*>(eh + addr) = uh.s;
    *reinterpret_cast<short4*>(el + addr) = ul.s;
}

// z (NCHW) -> transposed tiled fp16 hi/lo [pixel][dim]:
// addr(halfs) = (px>>7)*32768 + (d>>5)*4096 + (px&127)*32 + (d&31)
// stores are non-temporal: written once, read once (much later, by gemm)
__global__ __launch_bounds__(256) void cvt_z_kernel(const float* __restrict__ z,
                                                    ushort* __restrict__ zh,
                                                    ushort* __restrict__ zl) {
    __shared__ float ls[64][65];
    const int t = threadIdx.x;
    const int bid = blockIdx.x;
    const int b = bid >> 8, cc = (bid >> 6) & 3, hh = bid & 63;
    const int col = t & 63, r0 = t >> 6;
    #pragma unroll
    for (int i = 0; i < 16; ++i) {
        const int r = i * 4 + r0;
        ls[r][col] = z[((size_t)(b * DIM + cc * 64 + r)) * HW + hh * 64 + col];
    }
    __syncthreads();
    const int pxl = t >> 2, cseg = t & 3;
    const int px = b * HW + hh * 64 + pxl;
    const int sg = cc * 2 + (cseg >> 1);
    union H8 { _Float16 h[8]; i32x4 v; } ha, hb, la, lb;
    #pragma unroll
    for (int j = 0; j < 16; ++j) {
        const float val = ls[cseg * 16 + j][pxl];
        const _Float16 h = (_Float16)val;
        const _Float16 l = (_Float16)(val - (float)h);
        if (j < 8) { ha.h[j] = h; la.h[j] = l; }
        else       { hb.h[j - 8] = h; lb.h[j - 8] = l; }
    }
    const size_t addr = (size_t)(px >> 7) * 32768 + sg * 4096 + (px & 127) * 32 + (cseg & 1) * 16;
    ntstore16(zh + addr,     ha.v);
    ntstore16(zh + addr + 8, hb.v);
    ntstore16(zl + addr,     la.v);
    ntstore16(zl + addr + 8, lb.v);
}

// MFMA distance pass: block = 128 pixels x 4096 codes, per-pixel top4.
// R4-proven structure; z fragment loads NON-TEMPORAL so the streaming z
// doesn't evict the 4MB code array from L2 (codes cached normally).
__global__ __launch_bounds__(256, 3) void gemm_kernel(const ushort* __restrict__ eh,
                                                      const ushort* __restrict__ el,
                                                      const ushort* __restrict__ zh,
                                                      const ushort* __restrict__ zl,
                                                      const float* __restrict__ ee,
                                                      const float* __restrict__ zz,
                                                      float* __restrict__ top4v,
                                                      int* __restrict__ top4i) {
    __shared__ __align__(16) char smA_h[8192], smA_l[8192], smB_h[8192], smB_l[8192];
    __shared__ float zz_s[128], ee_s[128];
    __shared__ float mv[2][128][4];
    __shared__ int   mi_[2][128][4];

    const int t = threadIdx.x;
    const int lane = t & 63, w = t >> 6, wr = w >> 1, wc = w & 1;
    const int l15 = lane & 15, l4 = lane >> 4;
    const int px0 = blockIdx.x * 128;

    if (t < 128) zz_s[t] = zz[px0 + t];

    float Tv[4][4]; int Ti[4][4];
    #pragma unroll
    for (int ni = 0; ni < 4; ++ni) {
        #pragma unroll
        for (int j = 0; j < 4; ++j) { Tv[ni][j] = 3.0e38f; Ti[ni][j] = 0; }
    }

    const size_t zbase = (size_t)blockIdx.x * 32768;

    for (int p = 0; p < 32; ++p) {
        f32x4 acc[4][4];
        #pragma unroll
        for (int mi = 0; mi < 4; ++mi)
            #pragma unroll
            for (int ni = 0; ni < 4; ++ni)
                acc[mi][ni] = (f32x4){0.0f, 0.0f, 0.0f, 0.0f};

        for (int s = 0; s < 8; ++s) {
            __syncthreads();   // protect sm*/ee_s from previous chunk's readers
            const size_t ga = (size_t)p * 32768 + s * 4096 + t * 16;
            const size_t gb = zbase + s * 4096 + t * 16;
            const i32x4 a0 = *reinterpret_cast<const i32x4*>(eh + ga);
            const i32x4 a1 = *reinterpret_cast<const i32x4*>(eh + ga + 8);
            const i32x4 a2 = *reinterpret_cast<const i32x4*>(el + ga);
            const i32x4 a3 = *reinterpret_cast<const i32x4*>(el + ga + 8);
            const i32x4 b0 = ntload16(zh + gb);
            const i32x4 b1 = ntload16(zh + gb + 8);
            const i32x4 b2 = ntload16(zl + gb);
            const i32x4 b3 = ntload16(zl + gb + 8);
            const int d0 = SWZ(t * 32), d1 = SWZ(t * 32 + 16);
            *reinterpret_cast<i32x4*>(smA_h + d0) = a0;
            *reinterpret_cast<i32x4*>(smA_h + d1) = a1;
            *reinterpret_cast<i32x4*>(smA_l + d0) = a2;
            *reinterpret_cast<i32x4*>(smA_l + d1) = a3;
            *reinterpret_cast<i32x4*>(smB_h + d0) = b0;
            *reinterpret_cast<i32x4*>(smB_h + d1) = b1;
            *reinterpret_cast<i32x4*>(smB_l + d0) = b2;
            *reinterpret_cast<i32x4*>(smB_l + d1) = b3;
            if (s == 0 && t < 128) ee_s[t] = ee[p * 128 + t];
            __syncthreads();

            f16x8 bH[4], bL[4];
            #pragma unroll
            for (int ni = 0; ni < 4; ++ni) {
                const int ob = SWZ((wc * 64 + ni * 16 + l15) * 64 + l4 * 16);
                bH[ni] = *reinterpret_cast<const f16x8*>(smB_h + ob);
                bL[ni] = *reinterpret_cast<const f16x8*>(smB_l + ob);
            }
            #pragma unroll
            for (int mi = 0; mi < 4; ++mi) {
                const int oa = SWZ((wr * 64 + mi * 16 + l15) * 64 + l4 * 16);
                const f16x8 aH = *reinterpret_cast<const f16x8*>(smA_h + oa);
                const f16x8 aL = *reinterpret_cast<const f16x8*>(smA_l + oa);
                #pragma unroll
                for (int ni = 0; ni < 4; ++ni) {
                    acc[mi][ni] = __builtin_amdgcn_mfma_f32_16x16x32_f16(aH, bH[ni], acc[mi][ni], 0, 0, 0);
                    acc[mi][ni] = __builtin_amdgcn_mfma_f32_16x16x32_f16(aH, bL[ni], acc[mi][ni], 0, 0, 0);
                    acc[mi][ni] = __builtin_amdgcn_mfma_f32_16x16x32_f16(aL, bH[ni], acc[mi][ni], 0, 0, 0);
                }
            }
        }
        // epilogue: d = fl(t - acc*2^-11), top4 update (ascending k)
        #pragma unroll
        for (int ni = 0; ni < 4; ++ni) {
            const float zzc = zz_s[wc * 64 + ni * 16 + l15];
            #pragma unroll
            for (int mi = 0; mi < 4; ++mi) {
                #pragma unroll
                for (int r = 0; r < 4; ++r) {
                    const int rowb = wr * 64 + mi * 16 + l4 * 4 + r;
                    const float tt = zzc + ee_s[rowb];
                    const float d = fmaf(acc[mi][ni][r], -4.8828125e-4f, tt);
                    const int k = p * 128 + rowb;
                    INS4(Tv[ni], Ti[ni], d, k);
                }
            }
        }
    }

    // cross-lane merge (lanes sharing the same col: l ^ 16, l ^ 32)
    #pragma unroll
    for (int ni = 0; ni < 4; ++ni) {
        #pragma unroll
        for (int m = 16; m <= 32; m <<= 1) {
            float ov[4]; int oi[4];
            #pragma unroll
            for (int j = 0; j < 4; ++j) {
                ov[j] = __shfl_xor(Tv[ni][j], m, 64);
                oi[j] = __shfl_xor(Ti[ni][j], m, 64);
            }
            #pragma unroll
            for (int j = 0; j < 4; ++j) INS4(Tv[ni], Ti[ni], ov[j], oi[j]);
        }
    }
    // cross-wave (wr) merge via LDS
    if (lane < 16) {
        #pragma unroll
        for (int ni = 0; ni < 4; ++ni) {
            const int c = wc * 64 + ni * 16 + lane;
            #pragma unroll
            for (int j = 0; j < 4; ++j) { mv[wr][c][j] = Tv[ni][j]; mi_[wr][c][j] = Ti[ni][j]; }
        }
    }
    __syncthreads();
    if (t < 128) {
        float fv[4]; int fi[4];
        #pragma unroll
        for (int j = 0; j < 4; ++j) { fv[j] = mv[0][t][j]; fi[j] = mi_[0][t][j]; }
        #pragma unroll
        for (int j = 0; j < 4; ++j) INS4(fv, fi, mv[1][t][j], mi_[1][t][j]);
        const int px = px0 + t;
        *reinterpret_cast<float4*>(top4v + (size_t)px * 4) = make_float4(fv[0], fv[1], fv[2], fv[3]);
        *reinterpret_cast<int4*>(top4i + (size_t)px * 4)   = make_int4(fi[0], fi[1], fi[2], fi[3]);
    }
}

// resolve: shortcut / np-exact candidate re-evaluation / rescan flagging
__global__ __launch_bounds__(256) void resolve_kernel(const float* __restrict__ z,
                                                      const float* __restrict__ emb,
                                                      const float* __restrict__ zz,
                                                      const float* __restrict__ ee,
                                                      const float* __restrict__ top4v,
                                                      const int* __restrict__ top4i,
                                                      int* __restrict__ idxf,
                                                      int* __restrict__ cnt,
                                                      int* __restrict__ rlist) {
    const int n = blockIdx.x * 256 + threadIdx.x;
    const float4 vv = *reinterpret_cast<const float4*>(top4v + (size_t)n * 4);
    const int4   ii = *reinterpret_cast<const int4*>(top4i + (size_t)n * 4);
    const float v[4] = {vv.x, vv.y, vv.z, vv.w};
    const int   id[4] = {ii.x, ii.y, ii.z, ii.w};
    const float lim = v[0] + EPSW;
    if (v[1] > lim) { idxf[n] = id[0]; return; }
    if (v[3] <= lim) {                       // can't certify top4 covers window
        idxf[n] = id[0];                     // provisional; rescan overwrites
        const int pos = atomicAdd(cnt, 1);
        rlist[pos] = n;
        return;
    }
    int ck[4]; int nc = 0;
    for (int j = 0; j < 4; ++j) if (v[j] <= lim) ck[nc++] = id[j];
    for (int a = 0; a < nc - 1; ++a)          // sort by k ascending
        for (int b2 = a + 1; b2 < nc; ++b2)
            if (ck[b2] < ck[a]) { int tmp = ck[a]; ck[a] = ck[b2]; ck[b2] = tmp; }
    float best = 0.0f; int bk = -1;
    for (int a = 0; a < nc; ++a) {
        const float d = np_dist(z, emb, zz, ee, n, ck[a]);
        if (bk < 0 || d < best) { best = d; bk = ck[a]; }
    }
    idxf[n] = bk;
}

// full np-exact rescan for flagged pixels (rare)
__global__ __launch_bounds__(256) void rescan_kernel(const float* __restrict__ z,
                                                     const float* __restrict__ emb,
                                                     const float* __restrict__ zz,
                                                     const float* __restrict__ ee,
                                                     const int* __restrict__ cnt,
                                                     const int* __restrict__ rlist,
                                                     int* __restrict__ idxf) {
#pragma clang fp contract(off)
    __shared__ float ls[DIM];
    __shared__ float bv[256];
    __shared__ int   bk[256];
    const int t = threadIdx.x;
    const int count = *cnt;
    for (int e = blockIdx.x; e < count; e += gridDim.x) {
        const int n = rlist[e];
        const int b = n >> 12, hw = n & (HW - 1);
        __syncthreads();
        ls[t] = z[((size_t)(b * DIM + t)) * HW + hw];
        __syncthreads();
        float bestd = 3.0e38f; int besti = -1;
        for (int j = 0; j < 16; ++j) {
            const int k = t + j * 256;
            const float* ep = emb + (size_t)k * DIM;
            float m = 0.0f;
            for (int i = 0; i < DIM; ++i) m = fmaf(ls[i], ep[i], m);
            const float d = (zz[n] + ee[k]) - 2.0f * m;
            if (besti < 0 || d < bestd) { bestd = d; besti = k; }
        }
        bv[t] = bestd; bk[t] = besti;
        __syncthreads();
        if (t == 0) {
            float bd = bv[0]; int bi = bk[0];
            for (int q = 1; q < 256; ++q)
                if (bv[q] < bd || (bv[q] == bd && bk[q] < bi)) { bd = bv[q]; bi = bk[q]; }
            idxf[n] = bi;
        }
    }
}

// gather z_q + idx output + loss partials
__global__ __launch_bounds__(256) void gather_kernel(const float* __restrict__ z,
                                                     const float* __restrict__ emb,
                                                     const int* __restrict__ idxf,
                                                     float* __restrict__ out,
                                                     float* __restrict__ part) {
    __shared__ int   idx_s[32];
    __shared__ float wred[4];
    const int tid = threadIdx.x;
    const int tx = tid & 31, ty = tid >> 5;
    const int m0 = blockIdx.x * 32;
    const int bimg = m0 >> 12, hw0 = m0 & (HW - 1);
    if (tid < 32) {
        const int ii = idxf[m0 + tid];
        idx_s[tid] = ii;
        out[NQ + m0 + tid] = (float)ii;
    }
    __syncthreads();
    float lsum = 0.0f;
    const size_t ebase = (size_t)idx_s[tx] * DIM;
    for (int it = 0; it < DIM / 8; ++it) {
        const int c = it * 8 + ty;
        const float e = emb[ebase + c];
        const size_t zoff = ((size_t)(bimg * DIM + c)) * HW + hw0 + tx;
        out[zoff] = e;
        const float diff = e - z[zoff];
        lsum += diff * diff;
    }
    #pragma unroll
    for (int off = 32; off >= 1; off >>= 1) lsum += __shfl_down(lsum, off, 64);
    if ((tid & 63) == 0) wred[tid >> 6] = lsum;
    __syncthreads();
    if (tid == 0) part[blockIdx.x] = wred[0] + wred[1] + wred[2] + wred[3];
}

__global__ __launch_bounds__(256) void loss_kernel(const float* __restrict__ part,
                                                   int nblk, float* __restrict__ out) {
    __shared__ float wred[4];
    const int tid = threadIdx.x;
    float s = 0.0f;
    for (int i = tid; i < nblk; i += 256) s += part[i];
    #pragma unroll
    for (int off = 32; off >= 1; off >>= 1) s += __shfl_down(s, off, 64);
    if ((tid & 63) == 0) wred[tid >> 6] = s;
    __syncthreads();
    if (tid == 0) {
        const float total = wred[0] + wred[1] + wred[2] + wred[3];
        out[NQ + NPIX] = 1.25f * total / 16777216.0f;
    }
}

// ---------------------------------------------------------------------------
// SAFE path: R3's proven fused VALU kernel (used when ws too small)
// ---------------------------------------------------------------------------
#define MP 32
#define KC 128
#define DC 32
__global__ __launch_bounds__(256) void safe_dist_kernel(const float* __restrict__ z,
                                                        const float* __restrict__ emb,
                                                        const float* __restrict__ ee,
                                                        const float* __restrict__ zz,
                                                        float* __restrict__ out,
                                                        float* __restrict__ part) {
    __shared__ float zs[MP][DIM + 4];
    __shared__ float est[DC][KC + 4];
    __shared__ float ee_s[KC];
    __shared__ float zz_s[MP];
    __shared__ float red_v[MP][33];
    __shared__ int   red_i[MP][33];
    __shared__ int   idx_s[MP];
    __shared__ float wred[4];

    const int tid = threadIdx.x;
    const int tx = tid & 31, ty = tid >> 5;
    const int m0 = blockIdx.x * MP;
    const int bimg = m0 >> 12, hw0 = m0 & (HW - 1);

    for (int c = ty; c < DIM; c += 8)
        zs[tx][c] = z[((size_t)(bimg * DIM + c)) * HW + hw0 + tx];
    if (tid < MP) zz_s[tid] = zz[m0 + tid];

    float minv[4]; int mini[4];
    #pragma unroll
    for (int p = 0; p < 4; ++p) { minv[p] = 3.0e38f; mini[p] = 0; }
    const int rl = tid >> 3, cl = tid & 7;

    for (int kc = 0; kc < KCODES / KC; ++kc) {
        float acc[4][4];
        #pragma unroll
        for (int p = 0; p < 4; ++p)
            #pragma unroll
            for (int q = 0; q < 4; ++q) acc[p][q] = 0.0f;
        for (int dc = 0; dc < DIM / DC; ++dc) {
            __syncthreads();
            if (dc == 0 && tid < KC) ee_s[tid] = ee[kc * KC + tid];
            #pragma unroll
            for (int it = 0; it < 4; ++it) {
                const int kl = it * 32 + rl;
                const float4 v = *reinterpret_cast<const float4*>(
                    emb + (size_t)(kc * KC + kl) * DIM + dc * DC + cl * 4);
                est[cl * 4 + 0][kl] = v.x;
                est[cl * 4 + 1][kl] = v.y;
                est[cl * 4 + 2][kl] = v.z;
                est[cl * 4 + 3][kl] = v.w;
            }
            __syncthreads();
            #pragma unroll
            for (int g = 0; g < DC / 4; ++g) {
                float4 zr[4];
                #pragma unroll
                for (int p = 0; p < 4; ++p)
                    zr[p] = *reinterpret_cast<const float4*>(&zs[ty * 4 + p][dc * DC + g * 4]);
                float4 er[4];
                #pragma unroll
                for (int j = 0; j < 4; ++j)
                    er[j] = *reinterpret_cast<const float4*>(&est[g * 4 + j][tx * 4]);
                #pragma unroll
                for (int p = 0; p < 4; ++p) {
                    acc[p][0] = fmaf(zr[p].x, er[0].x, acc[p][0]);
                    acc[p][0] = fmaf(zr[p].y, er[1].x, acc[p][0]);
                    acc[p][0] = fmaf(zr[p].z, er[2].x, acc[p][0]);
                    acc[p][0] = fmaf(zr[p].w, er[3].x, acc[p][0]);
                    acc[p][1] = fmaf(zr[p].x, er[0].y, acc[p][1]);
                    acc[p][1] = fmaf(zr[p].y, er[1].y, acc[p][1]);
                    acc[p][1] = fmaf(zr[p].z, er[2].y, acc[p][1]);
                    acc[p][1] = fmaf(zr[p].w, er[3].y, acc[p][1]);
                    acc[p][2] = fmaf(zr[p].x, er[0].z, acc[p][2]);
                    acc[p][2] = fmaf(zr[p].y, er[1].z, acc[p][2]);
                    acc[p][2] = fmaf(zr[p].z, er[2].z, acc[p][2]);
                    acc[p][2] = fmaf(zr[p].w, er[3].z, acc[p][2]);
                    acc[p][3] = fmaf(zr[p].x, er[0].w, acc[p][3]);
                    acc[p][3] = fmaf(zr[p].y, er[1].w, acc[p][3]);
                    acc[p][3] = fmaf(zr[p].z, er[2].w, acc[p][3]);
                    acc[p][3] = fmaf(zr[p].w, er[3].w, acc[p][3]);
                }
            }
        }
        #pragma unroll
        for (int q = 0; q < 4; ++q) {
            const int kg = kc * KC + tx * 4 + q;
            const float en = ee_s[tx * 4 + q];
            #pragma unroll
            for (int p = 0; p < 4; ++p) {
                const float t = zz_s[ty * 4 + p] + en;
                const float d = t - 2.0f * acc[p][q];
                if (d < minv[p]) { minv[p] = d; mini[p] = kg; }
            }
        }
    }
    #pragma unroll
    for (int p = 0; p < 4; ++p) {
        red_v[ty * 4 + p][tx] = minv[p];
        red_i[ty * 4 + p][tx] = mini[p];
    }
    __syncthreads();
    if (tid < MP) {
        float bvv = red_v[tid][0]; int bii = red_i[tid][0];
        for (int q = 1; q < 32; ++q) {
            const float vq = red_v[tid][q]; const int iq = red_i[tid][q];
            if (vq < bvv || (vq == bvv && iq < bii)) { bvv = vq; bii = iq; }
        }
        idx_s[tid] = bii;
        out[NQ + m0 + tid] = (float)bii;
    }
    __syncthreads();
    float lsum = 0.0f;
    const size_t ebase = (size_t)idx_s[tx] * DIM;
    for (int it = 0; it < DIM / 8; ++it) {
        const int c = it * 8 + ty;
        const float e = emb[ebase + c];
        out[((size_t)(bimg * DIM + c)) * HW + hw0 + tx] = e;
        const float diff = e - zs[tx][c];
        lsum += diff * diff;
    }
    #pragma unroll
    for (int off = 32; off >= 1; off >>= 1) lsum += __shfl_down(lsum, off, 64);
    if ((tid & 63) == 0) wred[tid >> 6] = lsum;
    __syncthreads();
    if (tid == 0) part[blockIdx.x] = wred[0] + wred[1] + wred[2] + wred[3];
}

// ---------------------------------------------------------------------------
extern "C" void kernel_launch(void* const* d_in, const int* in_sizes, int n_in,
                              void* d_out, int out_size, void* d_ws, size_t ws_size,
                              hipStream_t stream) {
    const float* z   = (const float*)d_in[0];
    const float* emb = (const float*)d_in[1];
    float* out = (float*)d_out;
    char*  ws  = (char*)d_ws;

    // shared small region
    float* zz   = (float*)(ws + 0);            // 256K
    float* ee   = (float*)(ws + 262144);       // 16K
    float* part = (float*)(ws + 278528);       // 8K
    int*   cnt  = (int*)  (ws + 286720);       // 4K
    int*   rlst = (int*)  (ws + 290816);       // 256K
    int*   idxf = (int*)  (ws + 552960);       // 256K
    float* t4v  = (float*)(ws + 1048576);      // 1M
    int*   t4i  = (int*)  (ws + 2097152);      // 1M
    ushort* eh  = (ushort*)(ws + 3145728);     // 2M
    ushort* el  = (ushort*)(ws + 5242880);     // 2M
    ushort* zh  = (ushort*)(ws + 7340032);     // 32M
    ushort* zl  = (ushort*)(ws + 40894464);    // 32M
    const size_t REQ = 74448896;               // ~71 MB

    ee_np_kernel<<<KCODES / 256, 256, 0, stream>>>(emb, ee);
    zz_np_kernel<<<NPIX / 256, 256, 0, stream>>>(z, zz);

    if (ws_size >= REQ) {
        hipMemsetAsync(cnt, 0, 4, stream);
        cvt_emb_kernel<<<KCODES / 4, 256, 0, stream>>>(emb, eh, el);
        cvt_z_kernel<<<4096, 256, 0, stream>>>(z, zh, zl);
        gemm_kernel<<<NPIX / 128, 256, 0, stream>>>(eh, el, zh, zl, ee, zz, t4v, t4i);
        resolve_kernel<<<NPIX / 256, 256, 0, stream>>>(z, emb, zz, ee, t4v, t4i, idxf, cnt, rlst);
        rescan_kernel<<<64, 256, 0, stream>>>(z, emb, zz, ee, cnt, rlst, idxf);
        gather_kernel<<<NPIX / 32, 256, 0, stream>>>(z, emb, idxf, out, part);
        loss_kernel<<<1, 256, 0, stream>>>(part, NPIX / 32, out);
    } else {
        safe_dist_kernel<<<NPIX / MP, 256, 0, stream>>>(z, emb, ee, zz, out, part);
        loss_kernel<<<1, 256, 0, stream>>>(part, NPIX / MP, out);
    }
}

// Round 9
// 865.168 us; speedup vs baseline: 1.6667x; 1.3808x over previous
//
#include <hip/hip_runtime.h>
#include <math.h>

#define KCODES 4096
#define DIM    256
#define HW     4096
#define NPIX   65536
#define NQ     16777216   // 16*256*64*64
#define EPSW   1.0e-4f    // candidate window (>= 2*(ulp(256)+2*deltam))

typedef _Float16 f16x8 __attribute__((ext_vector_type(8)));
typedef float    f32x4 __attribute__((ext_vector_type(4)));
typedef int      i32x4 __attribute__((ext_vector_type(4)));

static __device__ __forceinline__ i32x4 ntload16(const void* p) {
    return __builtin_nontemporal_load(reinterpret_cast<const i32x4*>(p));
}
static __device__ __forceinline__ void ntstore16(void* p, i32x4 v) {
    __builtin_nontemporal_store(v, reinterpret_cast<i32x4*>(p));
}

// XOR swizzle on tile-local byte offset: spreads 64B rows across banks
#define SWZ(x) ((x) ^ ((((x) >> 6) & 7) << 4))

// top4 insert, strict < (keeps lowest k on equal d given ascending-k feed)
#define INS4(V, I, dd, kk) do { \
  if ((dd) < V[3]) { \
    if ((dd) < V[1]) { \
      V[3]=V[2]; I[3]=I[2]; V[2]=V[1]; I[2]=I[1]; \
      if ((dd) < V[0]) { V[1]=V[0]; I[1]=I[0]; V[0]=(dd); I[0]=(kk); } \
      else             { V[1]=(dd); I[1]=(kk); } \
    } else { \
      if ((dd) < V[2]) { V[3]=V[2]; I[3]=I[2]; V[2]=(dd); I[2]=(kk); } \
      else             { V[3]=(dd); I[3]=(kk); } \
    } } } while(0)

// ---------------------------------------------------------------------------
// np-exact helpers (bit-replicate numpy f32 semantics — proven in R3)
// ---------------------------------------------------------------------------
__global__ __launch_bounds__(256) void ee_np_kernel(const float* __restrict__ emb,
                                                    float* __restrict__ ee) {
#pragma clang fp contract(off)
    const int k = blockIdx.x * 256 + threadIdx.x;
    const float* a = emb + (size_t)k * DIM;
    float res[2];
    #pragma unroll
    for (int h = 0; h < 2; ++h) {
        const float* b = a + h * 128;
        float r[8];
        #pragma unroll
        for (int j = 0; j < 8; ++j) { const float x = b[j]; r[j] = x * x; }
        for (int i = 8; i < 128; i += 8) {
            #pragma unroll
            for (int j = 0; j < 8; ++j) { const float x = b[i + j]; r[j] += x * x; }
        }
        res[h] = ((r[0] + r[1]) + (r[2] + r[3])) + ((r[4] + r[5]) + (r[6] + r[7]));
    }
    ee[k] = res[0] + res[1];
}

__global__ __launch_bounds__(256) void zz_np_kernel(const float* __restrict__ z,
                                                    float* __restrict__ zz) {
#pragma clang fp contract(off)
    const int n  = blockIdx.x * 256 + threadIdx.x;
    const int b  = n >> 12;
    const int hw = n & (HW - 1);
    const float* base = z + (size_t)b * DIM * HW + hw;
    float res[2];
    #pragma unroll
    for (int h = 0; h < 2; ++h) {
        const float* p = base + (size_t)(h * 128) * HW;
        float r[8];
        #pragma unroll
        for (int j = 0; j < 8; ++j) { const float x = p[(size_t)j * HW]; r[j] = x * x; }
        for (int i = 8; i < 128; i += 8) {
            #pragma unroll
            for (int j = 0; j < 8; ++j) { const float x = p[(size_t)(i + j) * HW]; r[j] += x * x; }
        }
        res[h] = ((r[0] + r[1]) + (r[2] + r[3])) + ((r[4] + r[5]) + (r[6] + r[7]));
    }
    zz[n] = res[0] + res[1];
}

__device__ float np_dist(const float* __restrict__ z, const float* __restrict__ emb,
                         const float* __restrict__ zz, const float* __restrict__ ee,
                         int n, int k) {
    const int b = n >> 12, hw = n & (HW - 1);
    const float* zp = z + (size_t)b * DIM * HW + hw;
    const float* ep = emb + (size_t)k * DIM;
    float m = 0.0f;
    for (int i = 0; i < DIM; ++i) m = fmaf(zp[(size_t)i * HW], ep[i], m);
    const float t = zz[n] + ee[k];
    return t - 2.0f * m;   // == fl(t - 2m) either way (product exact)
}

// ---------------------------------------------------------------------------
// FAST path kernels
// ---------------------------------------------------------------------------
// emb -> tiled fp16 hi/lo, scaled by 4096 (exact pow2). Tile layout:
// addr(halfs) = (k>>7)*32768 + (d>>5)*4096 + (k&127)*32 + (d&31)
__global__ __launch_bounds__(256) void cvt_emb_kernel(const float* __restrict__ emb,
                                                      ushort* __restrict__ eh,
                                                      ushort* __restrict__ el) {
    const int t = threadIdx.x;
    const int k = blockIdx.x * 4 + (t >> 6);
    const int seg = t & 63;                       // 4-elem segment
    const float4 v = *reinterpret_cast<const float4*>(emb + (size_t)k * DIM + seg * 4);
    union H4 { _Float16 h[4]; short4 s; } uh, ul;
    const float vv[4] = {v.x, v.y, v.z, v.w};
    #pragma unroll
    for (int j = 0; j < 4; ++j) {
        const float es = vv[j] * 4096.0f;
        const _Float16 h = (_Float16)es;
        uh.h[j] = h;
        ul.h[j] = (_Float16)(es - (float)h);
    }
    const int s = seg >> 3, din = (seg & 7) * 4;
    const size_t addr = (size_t)(k >> 7) * 32768 + s * 4096 + (k & 127) * 32 + din;
    *reinterpret_cast<short4*>(eh + addr) = uh.s;
    *reinterpret_cast<short4*>(el + addr) = ul.s;
}

// z (NCHW) -> transposed tiled fp16 hi/lo [pixel][dim]:
// addr(halfs) = (px>>7)*32768 + (d>>5)*4096 + (px&127)*32 + (d&31)
// stores non-temporal: written once, read once much later
__global__ __launch_bounds__(256) void cvt_z_kernel(const float* __restrict__ z,
                                                    ushort* __restrict__ zh,
                                                    ushort* __restrict__ zl) {
    __shared__ float ls[64][65];
    const int t = threadIdx.x;
    const int bid = blockIdx.x;
    const int b = bid >> 8, cc = (bid >> 6) & 3, hh = bid & 63;
    const int col = t & 63, r0 = t >> 6;
    #pragma unroll
    for (int i = 0; i < 16; ++i) {
        const int r = i * 4 + r0;
        ls[r][col] = z[((size_t)(b * DIM + cc * 64 + r)) * HW + hh * 64 + col];
    }
    __syncthreads();
    const int pxl = t >> 2, cseg = t & 3;
    const int px = b * HW + hh * 64 + pxl;
    const int sg = cc * 2 + (cseg >> 1);
    union H8 { _Float16 h[8]; i32x4 v; } ha, hb, la, lb;
    #pragma unroll
    for (int j = 0; j < 16; ++j) {
        const float val = ls[cseg * 16 + j][pxl];
        const _Float16 h = (_Float16)val;
        const _Float16 l = (_Float16)(val - (float)h);
        if (j < 8) { ha.h[j] = h; la.h[j] = l; }
        else       { hb.h[j - 8] = h; lb.h[j - 8] = l; }
    }
    const size_t addr = (size_t)(px >> 7) * 32768 + sg * 4096 + (px & 127) * 32 + (cseg & 1) * 16;
    ntstore16(zh + addr,     ha.v);
    ntstore16(zh + addr + 8, hb.v);
    ntstore16(zl + addr,     la.v);
    ntstore16(zl + addr + 8, lb.v);
}

// MFMA distance pass: R4-proven structure (565us), single change: z fragment
// loads are NON-TEMPORAL (evict-first) so the read-once z stream doesn't evict
// the 4MB code array from L2. launch_bounds kept at (256,2) — R8's (256,3)
// spilled (VGPR 84, WRITE_SIZE 72MB scratch canary).
__global__ __launch_bounds__(256, 2) void gemm_kernel(const ushort* __restrict__ eh,
                                                      const ushort* __restrict__ el,
                                                      const ushort* __restrict__ zh,
                                                      const ushort* __restrict__ zl,
                                                      const float* __restrict__ ee,
                                                      const float* __restrict__ zz,
                                                      float* __restrict__ top4v,
                                                      int* __restrict__ top4i) {
    __shared__ __align__(16) char smA_h[8192], smA_l[8192], smB_h[8192], smB_l[8192];
    __shared__ float zz_s[128], ee_s[128];
    __shared__ float mv[2][128][4];
    __shared__ int   mi_[2][128][4];

    const int t = threadIdx.x;
    const int lane = t & 63, w = t >> 6, wr = w >> 1, wc = w & 1;
    const int l15 = lane & 15, l4 = lane >> 4;
    const int px0 = blockIdx.x * 128;

    if (t < 128) zz_s[t] = zz[px0 + t];

    float Tv[4][4]; int Ti[4][4];
    #pragma unroll
    for (int ni = 0; ni < 4; ++ni) {
        #pragma unroll
        for (int j = 0; j < 4; ++j) { Tv[ni][j] = 3.0e38f; Ti[ni][j] = 0; }
    }

    const size_t zbase = (size_t)blockIdx.x * 32768;

    for (int p = 0; p < 32; ++p) {
        f32x4 acc[4][4];
        #pragma unroll
        for (int mi = 0; mi < 4; ++mi)
            #pragma unroll
            for (int ni = 0; ni < 4; ++ni)
                acc[mi][ni] = (f32x4){0.0f, 0.0f, 0.0f, 0.0f};

        for (int s = 0; s < 8; ++s) {
            __syncthreads();   // protect sm*/ee_s from previous chunk's readers
            const size_t ga = (size_t)p * 32768 + s * 4096 + t * 16;
            const size_t gb = zbase + s * 4096 + t * 16;
            const i32x4 a0 = *reinterpret_cast<const i32x4*>(eh + ga);
            const i32x4 a1 = *reinterpret_cast<const i32x4*>(eh + ga + 8);
            const i32x4 a2 = *reinterpret_cast<const i32x4*>(el + ga);
            const i32x4 a3 = *reinterpret_cast<const i32x4*>(el + ga + 8);
            const i32x4 b0 = ntload16(zh + gb);
            const i32x4 b1 = ntload16(zh + gb + 8);
            const i32x4 b2 = ntload16(zl + gb);
            const i32x4 b3 = ntload16(zl + gb + 8);
            const int d0 = SWZ(t * 32), d1 = SWZ(t * 32 + 16);
            *reinterpret_cast<i32x4*>(smA_h + d0) = a0;
            *reinterpret_cast<i32x4*>(smA_h + d1) = a1;
            *reinterpret_cast<i32x4*>(smA_l + d0) = a2;
            *reinterpret_cast<i32x4*>(smA_l + d1) = a3;
            *reinterpret_cast<i32x4*>(smB_h + d0) = b0;
            *reinterpret_cast<i32x4*>(smB_h + d1) = b1;
            *reinterpret_cast<i32x4*>(smB_l + d0) = b2;
            *reinterpret_cast<i32x4*>(smB_l + d1) = b3;
            if (s == 0 && t < 128) ee_s[t] = ee[p * 128 + t];
            __syncthreads();

            f16x8 bH[4], bL[4];
            #pragma unroll
            for (int ni = 0; ni < 4; ++ni) {
                const int ob = SWZ((wc * 64 + ni * 16 + l15) * 64 + l4 * 16);
                bH[ni] = *reinterpret_cast<const f16x8*>(smB_h + ob);
                bL[ni] = *reinterpret_cast<const f16x8*>(smB_l + ob);
            }
            #pragma unroll
            for (int mi = 0; mi < 4; ++mi) {
                const int oa = SWZ((wr * 64 + mi * 16 + l15) * 64 + l4 * 16);
                const f16x8 aH = *reinterpret_cast<const f16x8*>(smA_h + oa);
                const f16x8 aL = *reinterpret_cast<const f16x8*>(smA_l + oa);
                #pragma unroll
                for (int ni = 0; ni < 4; ++ni) {
                    acc[mi][ni] = __builtin_amdgcn_mfma_f32_16x16x32_f16(aH, bH[ni], acc[mi][ni], 0, 0, 0);
                    acc[mi][ni] = __builtin_amdgcn_mfma_f32_16x16x32_f16(aH, bL[ni], acc[mi][ni], 0, 0, 0);
                    acc[mi][ni] = __builtin_amdgcn_mfma_f32_16x16x32_f16(aL, bH[ni], acc[mi][ni], 0, 0, 0);
                }
            }
        }
        // epilogue: d = fl(t - acc*2^-11), top4 update (ascending k)
        #pragma unroll
        for (int ni = 0; ni < 4; ++ni) {
            const float zzc = zz_s[wc * 64 + ni * 16 + l15];
            #pragma unroll
            for (int mi = 0; mi < 4; ++mi) {
                #pragma unroll
                for (int r = 0; r < 4; ++r) {
                    const int rowb = wr * 64 + mi * 16 + l4 * 4 + r;
                    const float tt = zzc + ee_s[rowb];
                    const float d = fmaf(acc[mi][ni][r], -4.8828125e-4f, tt);
                    const int k = p * 128 + rowb;
                    INS4(Tv[ni], Ti[ni], d, k);
                }
            }
        }
    }

    // cross-lane merge (lanes sharing the same col: l ^ 16, l ^ 32)
    #pragma unroll
    for (int ni = 0; ni < 4; ++ni) {
        #pragma unroll
        for (int m = 16; m <= 32; m <<= 1) {
            float ov[4]; int oi[4];
            #pragma unroll
            for (int j = 0; j < 4; ++j) {
                ov[j] = __shfl_xor(Tv[ni][j], m, 64);
                oi[j] = __shfl_xor(Ti[ni][j], m, 64);
            }
            #pragma unroll
            for (int j = 0; j < 4; ++j) INS4(Tv[ni], Ti[ni], ov[j], oi[j]);
        }
    }
    // cross-wave (wr) merge via LDS
    if (lane < 16) {
        #pragma unroll
        for (int ni = 0; ni < 4; ++ni) {
            const int c = wc * 64 + ni * 16 + lane;
            #pragma unroll
            for (int j = 0; j < 4; ++j) { mv[wr][c][j] = Tv[ni][j]; mi_[wr][c][j] = Ti[ni][j]; }
        }
    }
    __syncthreads();
    if (t < 128) {
        float fv[4]; int fi[4];
        #pragma unroll
        for (int j = 0; j < 4; ++j) { fv[j] = mv[0][t][j]; fi[j] = mi_[0][t][j]; }
        #pragma unroll
        for (int j = 0; j < 4; ++j) INS4(fv, fi, mv[1][t][j], mi_[1][t][j]);
        const int px = px0 + t;
        *reinterpret_cast<float4*>(top4v + (size_t)px * 4) = make_float4(fv[0], fv[1], fv[2], fv[3]);
        *reinterpret_cast<int4*>(top4i + (size_t)px * 4)   = make_int4(fi[0], fi[1], fi[2], fi[3]);
    }
}

// resolve: shortcut / np-exact candidate re-evaluation / rescan flagging
__global__ __launch_bounds__(256) void resolve_kernel(const float* __restrict__ z,
                                                      const float* __restrict__ emb,
                                                      const float* __restrict__ zz,
                                                      const float* __restrict__ ee,
                                                      const float* __restrict__ top4v,
                                                      const int* __restrict__ top4i,
                                                      int* __restrict__ idxf,
                                                      int* __restrict__ cnt,
                                                      int* __restrict__ rlist) {
    const int n = blockIdx.x * 256 + threadIdx.x;
    const float4 vv = *reinterpret_cast<const float4*>(top4v + (size_t)n * 4);
    const int4   ii = *reinterpret_cast<const int4*>(top4i + (size_t)n * 4);
    const float v[4] = {vv.x, vv.y, vv.z, vv.w};
    const int   id[4] = {ii.x, ii.y, ii.z, ii.w};
    const float lim = v[0] + EPSW;
    if (v[1] > lim) { idxf[n] = id[0]; return; }
    if (v[3] <= lim) {                       // can't certify top4 covers window
        idxf[n] = id[0];                     // provisional; rescan overwrites
        const int pos = atomicAdd(cnt, 1);
        rlist[pos] = n;
        return;
    }
    int ck[4]; int nc = 0;
    for (int j = 0; j < 4; ++j) if (v[j] <= lim) ck[nc++] = id[j];
    for (int a = 0; a < nc - 1; ++a)          // sort by k ascending
        for (int b2 = a + 1; b2 < nc; ++b2)
            if (ck[b2] < ck[a]) { int tmp = ck[a]; ck[a] = ck[b2]; ck[b2] = tmp; }
    float best = 0.0f; int bk = -1;
    for (int a = 0; a < nc; ++a) {
        const float d = np_dist(z, emb, zz, ee, n, ck[a]);
        if (bk < 0 || d < best) { best = d; bk = ck[a]; }
    }
    idxf[n] = bk;
}

// full np-exact rescan for flagged pixels (rare)
__global__ __launch_bounds__(256) void rescan_kernel(const float* __restrict__ z,
                                                     const float* __restrict__ emb,
                                                     const float* __restrict__ zz,
                                                     const float* __restrict__ ee,
                                                     const int* __restrict__ cnt,
                                                     const int* __restrict__ rlist,
                                                     int* __restrict__ idxf) {
#pragma clang fp contract(off)
    __shared__ float ls[DIM];
    __shared__ float bv[256];
    __shared__ int   bk[256];
    const int t = threadIdx.x;
    const int count = *cnt;
    for (int e = blockIdx.x; e < count; e += gridDim.x) {
        const int n = rlist[e];
        const int b = n >> 12, hw = n & (HW - 1);
        __syncthreads();
        ls[t] = z[((size_t)(b * DIM + t)) * HW + hw];
        __syncthreads();
        float bestd = 3.0e38f; int besti = -1;
        for (int j = 0; j < 16; ++j) {
            const int k = t + j * 256;
            const float* ep = emb + (size_t)k * DIM;
            float m = 0.0f;
            for (int i = 0; i < DIM; ++i) m = fmaf(ls[i], ep[i], m);
            const float d = (zz[n] + ee[k]) - 2.0f * m;
            if (besti < 0 || d < bestd) { bestd = d; besti = k; }
        }
        bv[t] = bestd; bk[t] = besti;
        __syncthreads();
        if (t == 0) {
            float bd = bv[0]; int bi = bk[0];
            for (int q = 1; q < 256; ++q)
                if (bv[q] < bd || (bv[q] == bd && bk[q] < bi)) { bd = bv[q]; bi = bk[q]; }
            idxf[n] = bi;
        }
    }
}

// gather z_q + idx output + loss partials
__global__ __launch_bounds__(256) void gather_kernel(const float* __restrict__ z,
                                                     const float* __restrict__ emb,
                                                     const int* __restrict__ idxf,
                                                     float* __restrict__ out,
                                                     float* __restrict__ part) {
    __shared__ int   idx_s[32];
    __shared__ float wred[4];
    const int tid = threadIdx.x;
    const int tx = tid & 31, ty = tid >> 5;
    const int m0 = blockIdx.x * 32;
    const int bimg = m0 >> 12, hw0 = m0 & (HW - 1);
    if (tid < 32) {
        const int ii = idxf[m0 + tid];
        idx_s[tid] = ii;
        out[NQ + m0 + tid] = (float)ii;
    }
    __syncthreads();
    float lsum = 0.0f;
    const size_t ebase = (size_t)idx_s[tx] * DIM;
    for (int it = 0; it < DIM / 8; ++it) {
        const int c = it * 8 + ty;
        const float e = emb[ebase + c];
        const size_t zoff = ((size_t)(bimg * DIM + c)) * HW + hw0 + tx;
        out[zoff] = e;
        const float diff = e - z[zoff];
        lsum += diff * diff;
    }
    #pragma unroll
    for (int off = 32; off >= 1; off >>= 1) lsum += __shfl_down(lsum, off, 64);
    if ((tid & 63) == 0) wred[tid >> 6] = lsum;
    __syncthreads();
    if (tid == 0) part[blockIdx.x] = wred[0] + wred[1] + wred[2] + wred[3];
}

__global__ __launch_bounds__(256) void loss_kernel(const float* __restrict__ part,
                                                   int nblk, float* __restrict__ out) {
    __shared__ float wred[4];
    const int tid = threadIdx.x;
    float s = 0.0f;
    for (int i = tid; i < nblk; i += 256) s += part[i];
    #pragma unroll
    for (int off = 32; off >= 1; off >>= 1) s += __shfl_down(s, off, 64);
    if ((tid & 63) == 0) wred[tid >> 6] = s;
    __syncthreads();
    if (tid == 0) {
        const float total = wred[0] + wred[1] + wred[2] + wred[3];
        out[NQ + NPIX] = 1.25f * total / 16777216.0f;
    }
}

// ---------------------------------------------------------------------------
// SAFE path: R3's proven fused VALU kernel (used when ws too small)
// ---------------------------------------------------------------------------
#define MP 32
#define KC 128
#define DC 32
__global__ __launch_bounds__(256) void safe_dist_kernel(const float* __restrict__ z,
                                                        const float* __restrict__ emb,
                                                        const float* __restrict__ ee,
                                                        const float* __restrict__ zz,
                                                        float* __restrict__ out,
                                                        float* __restrict__ part) {
    __shared__ float zs[MP][DIM + 4];
    __shared__ float est[DC][KC + 4];
    __shared__ float ee_s[KC];
    __shared__ float zz_s[MP];
    __shared__ float red_v[MP][33];
    __shared__ int   red_i[MP][33];
    __shared__ int   idx_s[MP];
    __shared__ float wred[4];

    const int tid = threadIdx.x;
    const int tx = tid & 31, ty = tid >> 5;
    const int m0 = blockIdx.x * MP;
    const int bimg = m0 >> 12, hw0 = m0 & (HW - 1);

    for (int c = ty; c < DIM; c += 8)
        zs[tx][c] = z[((size_t)(bimg * DIM + c)) * HW + hw0 + tx];
    if (tid < MP) zz_s[tid] = zz[m0 + tid];

    float minv[4]; int mini[4];
    #pragma unroll
    for (int p = 0; p < 4; ++p) { minv[p] = 3.0e38f; mini[p] = 0; }
    const int rl = tid >> 3, cl = tid & 7;

    for (int kc = 0; kc < KCODES / KC; ++kc) {
        float acc[4][4];
        #pragma unroll
        for (int p = 0; p < 4; ++p)
            #pragma unroll
            for (int q = 0; q < 4; ++q) acc[p][q] = 0.0f;
        for (int dc = 0; dc < DIM / DC; ++dc) {
            __syncthreads();
            if (dc == 0 && tid < KC) ee_s[tid] = ee[kc * KC + tid];
            #pragma unroll
            for (int it = 0; it < 4; ++it) {
                const int kl = it * 32 + rl;
                const float4 v = *reinterpret_cast<const float4*>(
                    emb + (size_t)(kc * KC + kl) * DIM + dc * DC + cl * 4);
                est[cl * 4 + 0][kl] = v.x;
                est[cl * 4 + 1][kl] = v.y;
                est[cl * 4 + 2][kl] = v.z;
                est[cl * 4 + 3][kl] = v.w;
            }
            __syncthreads();
            #pragma unroll
            for (int g = 0; g < DC / 4; ++g) {
                float4 zr[4];
                #pragma unroll
                for (int p = 0; p < 4; ++p)
                    zr[p] = *reinterpret_cast<const float4*>(&zs[ty * 4 + p][dc * DC + g * 4]);
                float4 er[4];
                #pragma unroll
                for (int j = 0; j < 4; ++j)
                    er[j] = *reinterpret_cast<const float4*>(&est[g * 4 + j][tx * 4]);
                #pragma unroll
                for (int p = 0; p < 4; ++p) {
                    acc[p][0] = fmaf(zr[p].x, er[0].x, acc[p][0]);
                    acc[p][0] = fmaf(zr[p].y, er[1].x, acc[p][0]);
                    acc[p][0] = fmaf(zr[p].z, er[2].x, acc[p][0]);
                    acc[p][0] = fmaf(zr[p].w, er[3].x, acc[p][0]);
                    acc[p][1] = fmaf(zr[p].x, er[0].y, acc[p][1]);
                    acc[p][1] = fmaf(zr[p].y, er[1].y, acc[p][1]);
                    acc[p][1] = fmaf(zr[p].z, er[2].y, acc[p][1]);
                    acc[p][1] = fmaf(zr[p].w, er[3].y, acc[p][1]);
                    acc[p][2] = fmaf(zr[p].x, er[0].z, acc[p][2]);
                    acc[p][2] = fmaf(zr[p].y, er[1].z, acc[p][2]);
                    acc[p][2] = fmaf(zr[p].z, er[2].z, acc[p][2]);
                    acc[p][2] = fmaf(zr[p].w, er[3].z, acc[p][2]);
                    acc[p][3] = fmaf(zr[p].x, er[0].w, acc[p][3]);
                    acc[p][3] = fmaf(zr[p].y, er[1].w, acc[p][3]);
                    acc[p][3] = fmaf(zr[p].z, er[2].w, acc[p][3]);
                    acc[p][3] = fmaf(zr[p].w, er[3].w, acc[p][3]);
                }
            }
        }
        #pragma unroll
        for (int q = 0; q < 4; ++q) {
            const int kg = kc * KC + tx * 4 + q;
            const float en = ee_s[tx * 4 + q];
            #pragma unroll
            for (int p = 0; p < 4; ++p) {
                const float t = zz_s[ty * 4 + p] + en;
                const float d = t - 2.0f * acc[p][q];
                if (d < minv[p]) { minv[p] = d; mini[p] = kg; }
            }
        }
    }
    #pragma unroll
    for (int p = 0; p < 4; ++p) {
        red_v[ty * 4 + p][tx] = minv[p];
        red_i[ty * 4 + p][tx] = mini[p];
    }
    __syncthreads();
    if (tid < MP) {
        float bvv = red_v[tid][0]; int bii = red_i[tid][0];
        for (int q = 1; q < 32; ++q) {
            const float vq = red_v[tid][q]; const int iq = red_i[tid][q];
            if (vq < bvv || (vq == bvv && iq < bii)) { bvv = vq; bii = iq; }
        }
        idx_s[tid] = bii;
        out[NQ + m0 + tid] = (float)bii;
    }
    __syncthreads();
    float lsum = 0.0f;
    const size_t ebase = (size_t)idx_s[tx] * DIM;
    for (int it = 0; it < DIM / 8; ++it) {
        const int c = it * 8 + ty;
        const float e = emb[ebase + c];
        out[((size_t)(bimg * DIM + c)) * HW + hw0 + tx] = e;
        const float diff = e - zs[tx][c];
        lsum += diff * diff;
    }
    #pragma unroll
    for (int off = 32; off >= 1; off >>= 1) lsum += __shfl_down(lsum, off, 64);
    if ((tid & 63) == 0) wred[tid >> 6] = lsum;
    __syncthreads();
    if (tid == 0) part[blockIdx.x] = wred[0] + wred[1] + wred[2] + wred[3];
}

// ---------------------------------------------------------------------------
extern "C" void kernel_launch(void* const* d_in, const int* in_sizes, int n_in,
                              void* d_out, int out_size, void* d_ws, size_t ws_size,
                              hipStream_t stream) {
    const float* z   = (const float*)d_in[0];
    const float* emb = (const float*)d_in[1];
    float* out = (float*)d_out;
    char*  ws  = (char*)d_ws;

    // shared small region
    float* zz   = (float*)(ws + 0);            // 256K
    float* ee   = (float*)(ws + 262144);       // 16K
    float* part = (float*)(ws + 278528);       // 8K
    int*   cnt  = (int*)  (ws + 286720);       // 4K
    int*   rlst = (int*)  (ws + 290816);       // 256K
    int*   idxf = (int*)  (ws + 552960);       // 256K
    float* t4v  = (float*)(ws + 1048576);      // 1M
    int*   t4i  = (int*)  (ws + 2097152);      // 1M
    ushort* eh  = (ushort*)(ws + 3145728);     // 2M
    ushort* el  = (ushort*)(ws + 5242880);     // 2M
    ushort* zh  = (ushort*)(ws + 7340032);     // 32M
    ushort* zl  = (ushort*)(ws + 40894464);    // 32M
    const size_t REQ = 74448896;               // ~71 MB

    ee_np_kernel<<<KCODES / 256, 256, 0, stream>>>(emb, ee);
    zz_np_kernel<<<NPIX / 256, 256, 0, stream>>>(z, zz);

    if (ws_size >= REQ) {
        hipMemsetAsync(cnt, 0, 4, stream);
        cvt_emb_kernel<<<KCODES / 4, 256, 0, stream>>>(emb, eh, el);
        cvt_z_kernel<<<4096, 256, 0, stream>>>(z, zh, zl);
        gemm_kernel<<<NPIX / 128, 256, 0, stream>>>(eh, el, zh, zl, ee, zz, t4v, t4i);
        resolve_kernel<<<NPIX / 256, 256, 0, stream>>>(z, emb, zz, ee, t4v, t4i, idxf, cnt, rlst);
        rescan_kernel<<<64, 256, 0, stream>>>(z, emb, zz, ee, cnt, rlst, idxf);
        gather_kernel<<<NPIX / 32, 256, 0, stream>>>(z, emb, idxf, out, part);
        loss_kernel<<<1, 256, 0, stream>>>(part, NPIX / 32, out);
    } else {
        safe_dist_kernel<<<NPIX / MP, 256, 0, stream>>>(z, emb, ee, zz, out, part);
        loss_kernel<<<1, 256, 0, stream>>>(part, NPIX / MP, out);
    }
}

// Round 10
// 748.147 us; speedup vs baseline: 1.9273x; 1.1564x over previous
//
#include <hip/hip_runtime.h>
#include <math.h>

#define KCODES 4096
#define DIM    256
#define HW     4096
#define NPIX   65536
#define NQ     16777216   // 16*256*64*64
#define EPSW   1.0e-4f    // candidate window (>= 2*(ulp(256)+2*deltam))

typedef _Float16 f16x8 __attribute__((ext_vector_type(8)));
typedef float    f32x4 __attribute__((ext_vector_type(4)));

// XOR swizzle on tile-local byte offset: spreads 64B rows across banks.
// Global tiled arrays are stored PRE-SWIZZLED (value of logical offset y at
// global offset SWZ(y)), so gemm stages with linear global_load_lds and
// reads LDS with SWZ offsets (rule: linear dest + inv-swz source + swz read).
#define SWZ(x) ((x) ^ ((((x) >> 6) & 7) << 4))

static __device__ __forceinline__ void gld16(const void* g, void* l) {
    __builtin_amdgcn_global_load_lds(
        (const __attribute__((address_space(1))) void*)g,
        (__attribute__((address_space(3))) void*)l, 16, 0, 0);
}

// top4 insert, strict < (keeps lowest k on equal d given ascending-k feed)
#define INS4(V, I, dd, kk) do { \
  if ((dd) < V[3]) { \
    if ((dd) < V[1]) { \
      V[3]=V[2]; I[3]=I[2]; V[2]=V[1]; I[2]=I[1]; \
      if ((dd) < V[0]) { V[1]=V[0]; I[1]=I[0]; V[0]=(dd); I[0]=(kk); } \
      else             { V[1]=(dd); I[1]=(kk); } \
    } else { \
      if ((dd) < V[2]) { V[3]=V[2]; I[3]=I[2]; V[2]=(dd); I[2]=(kk); } \
      else             { V[3]=(dd); I[3]=(kk); } \
    } } } while(0)

// ---------------------------------------------------------------------------
// np-exact helpers (bit-replicate numpy f32 semantics — proven in R3)
// ---------------------------------------------------------------------------
__global__ __launch_bounds__(256) void ee_np_kernel(const float* __restrict__ emb,
                                                    float* __restrict__ ee) {
#pragma clang fp contract(off)
    const int k = blockIdx.x * 256 + threadIdx.x;
    const float* a = emb + (size_t)k * DIM;
    float res[2];
    #pragma unroll
    for (int h = 0; h < 2; ++h) {
        const float* b = a + h * 128;
        float r[8];
        #pragma unroll
        for (int j = 0; j < 8; ++j) { const float x = b[j]; r[j] = x * x; }
        for (int i = 8; i < 128; i += 8) {
            #pragma unroll
            for (int j = 0; j < 8; ++j) { const float x = b[i + j]; r[j] += x * x; }
        }
        res[h] = ((r[0] + r[1]) + (r[2] + r[3])) + ((r[4] + r[5]) + (r[6] + r[7]));
    }
    ee[k] = res[0] + res[1];
}

__global__ __launch_bounds__(256) void zz_np_kernel(const float* __restrict__ z,
                                                    float* __restrict__ zz) {
#pragma clang fp contract(off)
    const int n  = blockIdx.x * 256 + threadIdx.x;
    const int b  = n >> 12;
    const int hw = n & (HW - 1);
    const float* base = z + (size_t)b * DIM * HW + hw;
    float res[2];
    #pragma unroll
    for (int h = 0; h < 2; ++h) {
        const float* p = base + (size_t)(h * 128) * HW;
        float r[8];
        #pragma unroll
        for (int j = 0; j < 8; ++j) { const float x = p[(size_t)j * HW]; r[j] = x * x; }
        for (int i = 8; i < 128; i += 8) {
            #pragma unroll
            for (int j = 0; j < 8; ++j) { const float x = p[(size_t)(i + j) * HW]; r[j] += x * x; }
        }
        res[h] = ((r[0] + r[1]) + (r[2] + r[3])) + ((r[4] + r[5]) + (r[6] + r[7]));
    }
    zz[n] = res[0] + res[1];
}

__device__ float np_dist(const float* __restrict__ z, const float* __restrict__ emb,
                         const float* __restrict__ zz, const float* __restrict__ ee,
                         int n, int k) {
    const int b = n >> 12, hw = n & (HW - 1);
    const float* zp = z + (size_t)b * DIM * HW + hw;
    const float* ep = emb + (size_t)k * DIM;
    float m = 0.0f;
    for (int i = 0; i < DIM; ++i) m = fmaf(zp[(size_t)i * HW], ep[i], m);
    const float t = zz[n] + ee[k];
    return t - 2.0f * m;   // == fl(t - 2m) either way (product exact)
}

// ---------------------------------------------------------------------------
// FAST path kernels
// ---------------------------------------------------------------------------
// emb -> tiled fp16 hi/lo, scaled by 4096 (exact pow2), PRE-SWIZZLED.
// logical addr(halfs) = (k>>7)*32768 + (d>>5)*4096 + (k&127)*32 + (d&31);
// stored at chunk + SWZ(local_byte)/2.
__global__ __launch_bounds__(256) void cvt_emb_kernel(const float* __restrict__ emb,
                                                      ushort* __restrict__ eh,
                                                      ushort* __restrict__ el) {
    const int t = threadIdx.x;
    const int k = blockIdx.x * 4 + (t >> 6);
    const int seg = t & 63;                       // 4-elem segment
    const float4 v = *reinterpret_cast<const float4*>(emb + (size_t)k * DIM + seg * 4);
    union H4 { _Float16 h[4]; short4 s; } uh, ul;
    const float vv[4] = {v.x, v.y, v.z, v.w};
    #pragma unroll
    for (int j = 0; j < 4; ++j) {
        const float es = vv[j] * 4096.0f;
        const _Float16 h = (_Float16)es;
        uh.h[j] = h;
        ul.h[j] = (_Float16)(es - (float)h);
    }
    const int s = seg >> 3;
    const int y  = (k & 127) * 64 + (seg & 7) * 8;        // logical byte in 8KB chunk
    const int ys = y ^ ((k & 7) << 4);                    // pre-swizzled
    const size_t addr = (size_t)(k >> 7) * 32768 + s * 4096 + (ys >> 1);
    *reinterpret_cast<short4*>(eh + addr) = uh.s;
    *reinterpret_cast<short4*>(el + addr) = ul.s;
}

// z (NCHW) -> transposed tiled fp16 hi/lo [pixel][dim], PRE-SWIZZLED.
__global__ __launch_bounds__(256) void cvt_z_kernel(const float* __restrict__ z,
                                                    ushort* __restrict__ zh,
                                                    ushort* __restrict__ zl) {
    __shared__ float ls[64][65];
    const int t = threadIdx.x;
    const int bid = blockIdx.x;
    const int b = bid >> 8, cc = (bid >> 6) & 3, hh = bid & 63;
    const int col = t & 63, r0 = t >> 6;
    #pragma unroll
    for (int i = 0; i < 16; ++i) {
        const int r = i * 4 + r0;
        ls[r][col] = z[((size_t)(b * DIM + cc * 64 + r)) * HW + hh * 64 + col];
    }
    __syncthreads();
    const int pxl = t >> 2, cseg = t & 3;
    const int px = b * HW + hh * 64 + pxl;
    const int sg = cc * 2 + (cseg >> 1);
    union H8 { _Float16 h[8]; int4 v; } ha, hb, la, lb;
    #pragma unroll
    for (int j = 0; j < 16; ++j) {
        const float val = ls[cseg * 16 + j][pxl];
        const _Float16 h = (_Float16)val;
        const _Float16 l = (_Float16)(val - (float)h);
        if (j < 8) { ha.h[j] = h; la.h[j] = l; }
        else       { hb.h[j - 8] = h; lb.h[j - 8] = l; }
    }
    const size_t chunk = (size_t)(px >> 7) * 32768 + sg * 4096;
    const int y1  = (px & 127) * 64 + (cseg & 1) * 32;    // logical byte of first 16B
    const int msk = (px & 7) << 4;
    const size_t a1 = chunk + ((y1 ^ msk) >> 1);
    const size_t a2 = chunk + (((y1 + 16) ^ msk) >> 1);
    *reinterpret_cast<int4*>(zh + a1) = ha.v;
    *reinterpret_cast<int4*>(zh + a2) = hb.v;
    *reinterpret_cast<int4*>(zl + a1) = la.v;
    *reinterpret_cast<int4*>(zl + a2) = lb.v;
}

// MFMA distance pass: R4-proven structure; staging via global_load_lds
// (linear dest, pre-swizzled source) — no staging VGPRs, no ds_writes.
__global__ __launch_bounds__(256, 2) void gemm_kernel(const ushort* __restrict__ eh,
                                                      const ushort* __restrict__ el,
                                                      const ushort* __restrict__ zh,
                                                      const ushort* __restrict__ zl,
                                                      const float* __restrict__ ee,
                                                      const float* __restrict__ zz,
                                                      float* __restrict__ top4v,
                                                      int* __restrict__ top4i) {
    __shared__ __align__(16) char smA_h[8192], smA_l[8192], smB_h[8192], smB_l[8192];
    __shared__ float zz_s[128], ee_s[128];
    __shared__ float mv[2][128][4];
    __shared__ int   mi_[2][128][4];

    const int t = threadIdx.x;
    const int lane = t & 63, w = t >> 6, wr = w >> 1, wc = w & 1;
    const int l15 = lane & 15, l4 = lane >> 4;
    const int px0 = blockIdx.x * 128;

    if (t < 128) zz_s[t] = zz[px0 + t];

    float Tv[4][4]; int Ti[4][4];
    #pragma unroll
    for (int ni = 0; ni < 4; ++ni) {
        #pragma unroll
        for (int j = 0; j < 4; ++j) { Tv[ni][j] = 3.0e38f; Ti[ni][j] = 0; }
    }

    const int lo = t * 16;            // per-lane linear byte offset (0..4080)
    const int wb = (t >> 6) * 1024;   // wave-uniform LDS base offset

    for (int p = 0; p < 32; ++p) {
        f32x4 acc[4][4];
        #pragma unroll
        for (int mi = 0; mi < 4; ++mi)
            #pragma unroll
            for (int ni = 0; ni < 4; ++ni)
                acc[mi][ni] = (f32x4){0.0f, 0.0f, 0.0f, 0.0f};

        for (int s = 0; s < 8; ++s) {
            __syncthreads();   // protect sm*/ee_s from previous chunk's readers
            const size_t cbA = ((size_t)p * 32768 + s * 4096) * 2;            // bytes
            const size_t cbB = ((size_t)blockIdx.x * 32768 + s * 4096) * 2;   // bytes
            const char* ebh = (const char*)eh + cbA;
            const char* ebl = (const char*)el + cbA;
            const char* zbh = (const char*)zh + cbB;
            const char* zbl = (const char*)zl + cbB;
            gld16(ebh + lo,        smA_h + wb);
            gld16(ebh + 4096 + lo, smA_h + 4096 + wb);
            gld16(ebl + lo,        smA_l + wb);
            gld16(ebl + 4096 + lo, smA_l + 4096 + wb);
            gld16(zbh + lo,        smB_h + wb);
            gld16(zbh + 4096 + lo, smB_h + 4096 + wb);
            gld16(zbl + lo,        smB_l + wb);
            gld16(zbl + 4096 + lo, smB_l + 4096 + wb);
            if (s == 0 && t < 128) ee_s[t] = ee[p * 128 + t];
            __syncthreads();

            f16x8 bH[4], bL[4];
            #pragma unroll
            for (int ni = 0; ni < 4; ++ni) {
                const int ob = SWZ((wc * 64 + ni * 16 + l15) * 64 + l4 * 16);
                bH[ni] = *reinterpret_cast<const f16x8*>(smB_h + ob);
                bL[ni] = *reinterpret_cast<const f16x8*>(smB_l + ob);
            }
            #pragma unroll
            for (int mi = 0; mi < 4; ++mi) {
                const int oa = SWZ((wr * 64 + mi * 16 + l15) * 64 + l4 * 16);
                const f16x8 aH = *reinterpret_cast<const f16x8*>(smA_h + oa);
                const f16x8 aL = *reinterpret_cast<const f16x8*>(smA_l + oa);
                #pragma unroll
                for (int ni = 0; ni < 4; ++ni) {
                    acc[mi][ni] = __builtin_amdgcn_mfma_f32_16x16x32_f16(aH, bH[ni], acc[mi][ni], 0, 0, 0);
                    acc[mi][ni] = __builtin_amdgcn_mfma_f32_16x16x32_f16(aH, bL[ni], acc[mi][ni], 0, 0, 0);
                    acc[mi][ni] = __builtin_amdgcn_mfma_f32_16x16x32_f16(aL, bH[ni], acc[mi][ni], 0, 0, 0);
                }
            }
        }
        // epilogue: d = fl(t - acc*2^-11), top4 update (ascending k)
        #pragma unroll
        for (int ni = 0; ni < 4; ++ni) {
            const float zzc = zz_s[wc * 64 + ni * 16 + l15];
            #pragma unroll
            for (int mi = 0; mi < 4; ++mi) {
                #pragma unroll
                for (int r = 0; r < 4; ++r) {
                    const int rowb = wr * 64 + mi * 16 + l4 * 4 + r;
                    const float tt = zzc + ee_s[rowb];
                    const float d = fmaf(acc[mi][ni][r], -4.8828125e-4f, tt);
                    const int k = p * 128 + rowb;
                    INS4(Tv[ni], Ti[ni], d, k);
                }
            }
        }
    }

    // cross-lane merge (lanes sharing the same col: l ^ 16, l ^ 32)
    #pragma unroll
    for (int ni = 0; ni < 4; ++ni) {
        #pragma unroll
        for (int m = 16; m <= 32; m <<= 1) {
            float ov[4]; int oi[4];
            #pragma unroll
            for (int j = 0; j < 4; ++j) {
                ov[j] = __shfl_xor(Tv[ni][j], m, 64);
                oi[j] = __shfl_xor(Ti[ni][j], m, 64);
            }
            #pragma unroll
            for (int j = 0; j < 4; ++j) INS4(Tv[ni], Ti[ni], ov[j], oi[j]);
        }
    }
    // cross-wave (wr) merge via LDS
    if (lane < 16) {
        #pragma unroll
        for (int ni = 0; ni < 4; ++ni) {
            const int c = wc * 64 + ni * 16 + lane;
            #pragma unroll
            for (int j = 0; j < 4; ++j) { mv[wr][c][j] = Tv[ni][j]; mi_[wr][c][j] = Ti[ni][j]; }
        }
    }
    __syncthreads();
    if (t < 128) {
        float fv[4]; int fi[4];
        #pragma unroll
        for (int j = 0; j < 4; ++j) { fv[j] = mv[0][t][j]; fi[j] = mi_[0][t][j]; }
        #pragma unroll
        for (int j = 0; j < 4; ++j) INS4(fv, fi, mv[1][t][j], mi_[1][t][j]);
        const int px = px0 + t;
        *reinterpret_cast<float4*>(top4v + (size_t)px * 4) = make_float4(fv[0], fv[1], fv[2], fv[3]);
        *reinterpret_cast<int4*>(top4i + (size_t)px * 4)   = make_int4(fi[0], fi[1], fi[2], fi[3]);
    }
}

// resolve: shortcut / np-exact candidate re-evaluation / rescan flagging
__global__ __launch_bounds__(256) void resolve_kernel(const float* __restrict__ z,
                                                      const float* __restrict__ emb,
                                                      const float* __restrict__ zz,
                                                      const float* __restrict__ ee,
                                                      const float* __restrict__ top4v,
                                                      const int* __restrict__ top4i,
                                                      int* __restrict__ idxf,
                                                      int* __restrict__ cnt,
                                                      int* __restrict__ rlist) {
    const int n = blockIdx.x * 256 + threadIdx.x;
    const float4 vv = *reinterpret_cast<const float4*>(top4v + (size_t)n * 4);
    const int4   ii = *reinterpret_cast<const int4*>(top4i + (size_t)n * 4);
    const float v[4] = {vv.x, vv.y, vv.z, vv.w};
    const int   id[4] = {ii.x, ii.y, ii.z, ii.w};
    const float lim = v[0] + EPSW;
    if (v[1] > lim) { idxf[n] = id[0]; return; }
    if (v[3] <= lim) {                       // can't certify top4 covers window
        idxf[n] = id[0];                     // provisional; rescan overwrites
        const int pos = atomicAdd(cnt, 1);
        rlist[pos] = n;
        return;
    }
    int ck[4]; int nc = 0;
    for (int j = 0; j < 4; ++j) if (v[j] <= lim) ck[nc++] = id[j];
    for (int a = 0; a < nc - 1; ++a)          // sort by k ascending
        for (int b2 = a + 1; b2 < nc; ++b2)
            if (ck[b2] < ck[a]) { int tmp = ck[a]; ck[a] = ck[b2]; ck[b2] = tmp; }
    float best = 0.0f; int bk = -1;
    for (int a = 0; a < nc; ++a) {
        const float d = np_dist(z, emb, zz, ee, n, ck[a]);
        if (bk < 0 || d < best) { best = d; bk = ck[a]; }
    }
    idxf[n] = bk;
}

// full np-exact rescan for flagged pixels (rare)
__global__ __launch_bounds__(256) void rescan_kernel(const float* __restrict__ z,
                                                     const float* __restrict__ emb,
                                                     const float* __restrict__ zz,
                                                     const float* __restrict__ ee,
                                                     const int* __restrict__ cnt,
                                                     const int* __restrict__ rlist,
                                                     int* __restrict__ idxf) {
#pragma clang fp contract(off)
    __shared__ float ls[DIM];
    __shared__ float bv[256];
    __shared__ int   bk[256];
    const int t = threadIdx.x;
    const int count = *cnt;
    for (int e = blockIdx.x; e < count; e += gridDim.x) {
        const int n = rlist[e];
        const int b = n >> 12, hw = n & (HW - 1);
        __syncthreads();
        ls[t] = z[((size_t)(b * DIM + t)) * HW + hw];
        __syncthreads();
        float bestd = 3.0e38f; int besti = -1;
        for (int j = 0; j < 16; ++j) {
            const int k = t + j * 256;
            const float* ep = emb + (size_t)k * DIM;
            float m = 0.0f;
            for (int i = 0; i < DIM; ++i) m = fmaf(ls[i], ep[i], m);
            const float d = (zz[n] + ee[k]) - 2.0f * m;
            if (besti < 0 || d < bestd) { bestd = d; besti = k; }
        }
        bv[t] = bestd; bk[t] = besti;
        __syncthreads();
        if (t == 0) {
            float bd = bv[0]; int bi = bk[0];
            for (int q = 1; q < 256; ++q)
                if (bv[q] < bd || (bv[q] == bd && bk[q] < bi)) { bd = bv[q]; bi = bk[q]; }
            idxf[n] = bi;
        }
    }
}

// gather z_q + idx output + loss partials
__global__ __launch_bounds__(256) void gather_kernel(const float* __restrict__ z,
                                                     const float* __restrict__ emb,
                                                     const int* __restrict__ idxf,
                                                     float* __restrict__ out,
                                                     float* __restrict__ part) {
    __shared__ int   idx_s[32];
    __shared__ float wred[4];
    const int tid = threadIdx.x;
    const int tx = tid & 31, ty = tid >> 5;
    const int m0 = blockIdx.x * 32;
    const int bimg = m0 >> 12, hw0 = m0 & (HW - 1);
    if (tid < 32) {
        const int ii = idxf[m0 + tid];
        idx_s[tid] = ii;
        out[NQ + m0 + tid] = (float)ii;
    }
    __syncthreads();
    float lsum = 0.0f;
    const size_t ebase = (size_t)idx_s[tx] * DIM;
    for (int it = 0; it < DIM / 8; ++it) {
        const int c = it * 8 + ty;
        const float e = emb[ebase + c];
        const size_t zoff = ((size_t)(bimg * DIM + c)) * HW + hw0 + tx;
        out[zoff] = e;
        const float diff = e - z[zoff];
        lsum += diff * diff;
    }
    #pragma unroll
    for (int off = 32; off >= 1; off >>= 1) lsum += __shfl_down(lsum, off, 64);
    if ((tid & 63) == 0) wred[tid >> 6] = lsum;
    __syncthreads();
    if (tid == 0) part[blockIdx.x] = wred[0] + wred[1] + wred[2] + wred[3];
}

__global__ __launch_bounds__(256) void loss_kernel(const float* __restrict__ part,
                                                   int nblk, float* __restrict__ out) {
    __shared__ float wred[4];
    const int tid = threadIdx.x;
    float s = 0.0f;
    for (int i = tid; i < nblk; i += 256) s += part[i];
    #pragma unroll
    for (int off = 32; off >= 1; off >>= 1) s += __shfl_down(s, off, 64);
    if ((tid & 63) == 0) wred[tid >> 6] = s;
    __syncthreads();
    if (tid == 0) {
        const float total = wred[0] + wred[1] + wred[2] + wred[3];
        out[NQ + NPIX] = 1.25f * total / 16777216.0f;
    }
}

// ---------------------------------------------------------------------------
// SAFE path: R3's proven fused VALU kernel (used when ws too small)
// ---------------------------------------------------------------------------
#define MP 32
#define KC 128
#define DC 32
__global__ __launch_bounds__(256) void safe_dist_kernel(const float* __restrict__ z,
                                                        const float* __restrict__ emb,
                                                        const float* __restrict__ ee,
                                                        const float* __restrict__ zz,
                                                        float* __restrict__ out,
                                                        float* __restrict__ part) {
    __shared__ float zs[MP][DIM + 4];
    __shared__ float est[DC][KC + 4];
    __shared__ float ee_s[KC];
    __shared__ float zz_s[MP];
    __shared__ float red_v[MP][33];
    __shared__ int   red_i[MP][33];
    __shared__ int   idx_s[MP];
    __shared__ float wred[4];

    const int tid = threadIdx.x;
    const int tx = tid & 31, ty = tid >> 5;
    const int m0 = blockIdx.x * MP;
    const int bimg = m0 >> 12, hw0 = m0 & (HW - 1);

    for (int c = ty; c < DIM; c += 8)
        zs[tx][c] = z[((size_t)(bimg * DIM + c)) * HW + hw0 + tx];
    if (tid < MP) zz_s[tid] = zz[m0 + tid];

    float minv[4]; int mini[4];
    #pragma unroll
    for (int p = 0; p < 4; ++p) { minv[p] = 3.0e38f; mini[p] = 0; }
    const int rl = tid >> 3, cl = tid & 7;

    for (int kc = 0; kc < KCODES / KC; ++kc) {
        float acc[4][4];
        #pragma unroll
        for (int p = 0; p < 4; ++p)
            #pragma unroll
            for (int q = 0; q < 4; ++q) acc[p][q] = 0.0f;
        for (int dc = 0; dc < DIM / DC; ++dc) {
            __syncthreads();
            if (dc == 0 && tid < KC) ee_s[tid] = ee[kc * KC + tid];
            #pragma unroll
            for (int it = 0; it < 4; ++it) {
                const int kl = it * 32 + rl;
                const float4 v = *reinterpret_cast<const float4*>(
                    emb + (size_t)(kc * KC + kl) * DIM + dc * DC + cl * 4);
                est[cl * 4 + 0][kl] = v.x;
                est[cl * 4 + 1][kl] = v.y;
                est[cl * 4 + 2][kl] = v.z;
                est[cl * 4 + 3][kl] = v.w;
            }
            __syncthreads();
            #pragma unroll
            for (int g = 0; g < DC / 4; ++g) {
                float4 zr[4];
                #pragma unroll
                for (int p = 0; p < 4; ++p)
                    zr[p] = *reinterpret_cast<const float4*>(&zs[ty * 4 + p][dc * DC + g * 4]);
                float4 er[4];
                #pragma unroll
                for (int j = 0; j < 4; ++j)
                    er[j] = *reinterpret_cast<const float4*>(&est[g * 4 + j][tx * 4]);
                #pragma unroll
                for (int p = 0; p < 4; ++p) {
                    acc[p][0] = fmaf(zr[p].x, er[0].x, acc[p][0]);
                    acc[p][0] = fmaf(zr[p].y, er[1].x, acc[p][0]);
                    acc[p][0] = fmaf(zr[p].z, er[2].x, acc[p][0]);
                    acc[p][0] = fmaf(zr[p].w, er[3].x, acc[p][0]);
                    acc[p][1] = fmaf(zr[p].x, er[0].y, acc[p][1]);
                    acc[p][1] = fmaf(zr[p].y, er[1].y, acc[p][1]);
                    acc[p][1] = fmaf(zr[p].z, er[2].y, acc[p][1]);
                    acc[p][1] = fmaf(zr[p].w, er[3].y, acc[p][1]);
                    acc[p][2] = fmaf(zr[p].x, er[0].z, acc[p][2]);
                    acc[p][2] = fmaf(zr[p].y, er[1].z, acc[p][2]);
                    acc[p][2] = fmaf(zr[p].z, er[2].z, acc[p][2]);
                    acc[p][2] = fmaf(zr[p].w, er[3].z, acc[p][2]);
                    acc[p][3] = fmaf(zr[p].x, er[0].w, acc[p][3]);
                    acc[p][3] = fmaf(zr[p].y, er[1].w, acc[p][3]);
                    acc[p][3] = fmaf(zr[p].z, er[2].w, acc[p][3]);
                    acc[p][3] = fmaf(zr[p].w, er[3].w, acc[p][3]);
                }
            }
        }
        #pragma unroll
        for (int q = 0; q < 4; ++q) {
            const int kg = kc * KC + tx * 4 + q;
            const float en = ee_s[tx * 4 + q];
            #pragma unroll
            for (int p = 0; p < 4; ++p) {
                const float t = zz_s[ty * 4 + p] + en;
                const float d = t - 2.0f * acc[p][q];
                if (d < minv[p]) { minv[p] = d; mini[p] = kg; }
            }
        }
    }
    #pragma unroll
    for (int p = 0; p < 4; ++p) {
        red_v[ty * 4 + p][tx] = minv[p];
        red_i[ty * 4 + p][tx] = mini[p];
    }
    __syncthreads();
    if (tid < MP) {
        float bvv = red_v[tid][0]; int bii = red_i[tid][0];
        for (int q = 1; q < 32; ++q) {
            const float vq = red_v[tid][q]; const int iq = red_i[tid][q];
            if (vq < bvv || (vq == bvv && iq < bii)) { bvv = vq; bii = iq; }
        }
        idx_s[tid] = bii;
        out[NQ + m0 + tid] = (float)bii;
    }
    __syncthreads();
    float lsum = 0.0f;
    const size_t ebase = (size_t)idx_s[tx] * DIM;
    for (int it = 0; it < DIM / 8; ++it) {
        const int c = it * 8 + ty;
        const float e = emb[ebase + c];
        out[((size_t)(bimg * DIM + c)) * HW + hw0 + tx] = e;
        const float diff = e - zs[tx][c];
        lsum += diff * diff;
    }
    #pragma unroll
    for (int off = 32; off >= 1; off >>= 1) lsum += __shfl_down(lsum, off, 64);
    if ((tid & 63) == 0) wred[tid >> 6] = lsum;
    __syncthreads();
    if (tid == 0) part[blockIdx.x] = wred[0] + wred[1] + wred[2] + wred[3];
}

// ---------------------------------------------------------------------------
extern "C" void kernel_launch(void* const* d_in, const int* in_sizes, int n_in,
                              void* d_out, int out_size, void* d_ws, size_t ws_size,
                              hipStream_t stream) {
    const float* z   = (const float*)d_in[0];
    const float* emb = (const float*)d_in[1];
    float* out = (float*)d_out;
    char*  ws  = (char*)d_ws;

    // shared small region
    float* zz   = (float*)(ws + 0);            // 256K
    float* ee   = (float*)(ws + 262144);       // 16K
    float* part = (float*)(ws + 278528);       // 8K
    int*   cnt  = (int*)  (ws + 286720);       // 4K
    int*   rlst = (int*)  (ws + 290816);       // 256K
    int*   idxf = (int*)  (ws + 552960);       // 256K
    float* t4v  = (float*)(ws + 1048576);      // 1M
    int*   t4i  = (int*)  (ws + 2097152);      // 1M
    ushort* eh  = (ushort*)(ws + 3145728);     // 2M
    ushort* el  = (ushort*)(ws + 5242880);     // 2M
    ushort* zh  = (ushort*)(ws + 7340032);     // 32M
    ushort* zl  = (ushort*)(ws + 40894464);    // 32M
    const size_t REQ = 74448896;               // ~71 MB

    ee_np_kernel<<<KCODES / 256, 256, 0, stream>>>(emb, ee);
    zz_np_kernel<<<NPIX / 256, 256, 0, stream>>>(z, zz);

    if (ws_size >= REQ) {
        hipMemsetAsync(cnt, 0, 4, stream);
        cvt_emb_kernel<<<KCODES / 4, 256, 0, stream>>>(emb, eh, el);
        cvt_z_kernel<<<4096, 256, 0, stream>>>(z, zh, zl);
        gemm_kernel<<<NPIX / 128, 256, 0, stream>>>(eh, el, zh, zl, ee, zz, t4v, t4i);
        resolve_kernel<<<NPIX / 256, 256, 0, stream>>>(z, emb, zz, ee, t4v, t4i, idxf, cnt, rlst);
        rescan_kernel<<<64, 256, 0, stream>>>(z, emb, zz, ee, cnt, rlst, idxf);
        gather_kernel<<<NPIX / 32, 256, 0, stream>>>(z, emb, idxf, out, part);
        loss_kernel<<<1, 256, 0, stream>>>(part, NPIX / 32, out);
    } else {
        safe_dist_kernel<<<NPIX / MP, 256, 0, stream>>>(z, emb, ee, zz, out, part);
        loss_kernel<<<1, 256, 0, stream>>>(part, NPIX / MP, out);
    }
}